// Round 2
// baseline (1761.183 us; speedup 1.0000x reference)
//
#include <hip/hip_runtime.h>

// MyTransformerEncoderLayer: B=128,S=77,D=1024,H=16,DH=64,F=4096,E=8,topK=2
// Round 4: split-K=4 for the three latency-bound K=4096/N=1024 GEMMs
// (MoE down-proj x2 passes + shared-expert down-proj). Their old shape gave
// only ~640 blocks (2.5/CU) -> MfmaUtil 15%. Split-K gives ~2560 blocks with
// fp32 atomicAdd accumulation (bias added by k-chunk 0 only).
// Expert-sorted MoE grouped GEMM + MFMA attention + m97-style bf16 BT GEMMs
// with pre-converted weights kept from round 3.
//
// New-path ws layout (bytes), FULL_NEED = 261,621,760 (~249.5 MiB):
//   [0,          75497472)   w1T  bf16 [9][4096][1024]   (ew1 + sw1, transposed)
//   [75497472,  150994944)   w2T  bf16 [9][1024][4096]   (ew2 + sw2, transposed)
//   [150994944, 157286400)   packed_w bf16 [3072][1024]
//   [157286400, 159383552)   out_w    bf16 [1024][1024]
//   [159383552, 179568640)   xn/ffn bf16 [9856][1024]
//   [179568640, 179731464)   MoE maps: tokmap[2][9984] i32 | rowgate[2][9984]
//                            f32 | tileinfo[2][96] int4 | ntiles[2]
//   [179830784, 261619712)   big: qkv(60555264)+ao(20185088); h(81788928,
//                            9984 rows) aliases
//   [261619712, 261621760)   top_i + gates
// Fallback (ws_size < FULL_NEED): round-1 pipeline (fp32 weights, guarded
// uint4 staging GEMM) with the new MFMA attention.

typedef float f32x4 __attribute__((ext_vector_type(4)));
typedef __bf16 bf16x8 __attribute__((ext_vector_type(8)));
typedef __bf16 bf16x4 __attribute__((ext_vector_type(4)));

#define NTOK 9856
#define DMODEL 1024
#define SEQ 77

__device__ __forceinline__ void gl16(const __bf16* g, __bf16* l) {
    __builtin_amdgcn_global_load_lds(
        (const __attribute__((address_space(1))) unsigned int*)g,
        (__attribute__((address_space(3))) unsigned int*)l, 16, 0, 0);
}

// ---------------------------------------------------------------- LayerNorm
__global__ __launch_bounds__(256)
void ln_kernel(const float* __restrict__ x, const float* __restrict__ w,
               const float* __restrict__ bb, __bf16* __restrict__ out)
{
    const int t = blockIdx.x, tid = threadIdx.x;
    const float4 v = ((const float4*)(x + (size_t)t * DMODEL))[tid];
    float s = v.x + v.y + v.z + v.w;
    float q = v.x*v.x + v.y*v.y + v.z*v.z + v.w*v.w;
#pragma unroll
    for (int off = 32; off; off >>= 1) {
        s += __shfl_xor(s, off, 64);
        q += __shfl_xor(q, off, 64);
    }
    __shared__ float rs[4], rq[4];
    const int wv = tid >> 6, lane = tid & 63;
    if (lane == 0) { rs[wv] = s; rq[wv] = q; }
    __syncthreads();
    s = rs[0] + rs[1] + rs[2] + rs[3];
    q = rq[0] + rq[1] + rq[2] + rq[3];
    const float mean = s * (1.f / 1024.f);
    const float rstd = rsqrtf(q * (1.f / 1024.f) - mean * mean + 1e-5f);
    const float4 wv4 = ((const float4*)w)[tid];
    const float4 bv4 = ((const float4*)bb)[tid];
    bf16x4 o;
    o[0] = (__bf16)((v.x - mean) * rstd * wv4.x + bv4.x);
    o[1] = (__bf16)((v.y - mean) * rstd * wv4.y + bv4.y);
    o[2] = (__bf16)((v.z - mean) * rstd * wv4.z + bv4.z);
    o[3] = (__bf16)((v.w - mean) * rstd * wv4.w + bv4.w);
    ((bf16x4*)out)[(size_t)t * 256 + tid] = o;
}

// ---------------------------------------------------------------- Router
__global__ __launch_bounds__(256)
void router_kernel(const float* __restrict__ x, const float* __restrict__ w,
                   const float* __restrict__ bb, const float* __restrict__ rw,
                   int* __restrict__ top_i, float* __restrict__ gates)
{
    const int b = blockIdx.x, tid = threadIdx.x;
    __shared__ float lnv[1024];
    __shared__ float red[8];
    __shared__ float pl[8][33];
    const float4 v = ((const float4*)(x + (size_t)b * SEQ * DMODEL))[tid];
    float s = v.x + v.y + v.z + v.w;
    float q = v.x*v.x + v.y*v.y + v.z*v.z + v.w*v.w;
#pragma unroll
    for (int off = 32; off; off >>= 1) {
        s += __shfl_xor(s, off, 64);
        q += __shfl_xor(q, off, 64);
    }
    const int wv = tid >> 6, lane = tid & 63;
    if (lane == 0) { red[wv] = s; red[4 + wv] = q; }
    __syncthreads();
    s = red[0] + red[1] + red[2] + red[3];
    q = red[4] + red[5] + red[6] + red[7];
    const float mean = s * (1.f / 1024.f);
    const float rstd = rsqrtf(q * (1.f / 1024.f) - mean * mean + 1e-5f);
    const float4 wv4 = ((const float4*)w)[tid];
    const float4 bv4 = ((const float4*)bb)[tid];
    lnv[4 * tid + 0] = (v.x - mean) * rstd * wv4.x + bv4.x;
    lnv[4 * tid + 1] = (v.y - mean) * rstd * wv4.y + bv4.y;
    lnv[4 * tid + 2] = (v.z - mean) * rstd * wv4.z + bv4.z;
    lnv[4 * tid + 3] = (v.w - mean) * rstd * wv4.w + bv4.w;
    __syncthreads();
    const int e = tid >> 5, g = tid & 31;
    float p = 0.f;
    for (int d = g; d < 1024; d += 32) p += lnv[d] * rw[(size_t)e * 1024 + d];
    pl[e][g] = p;
    __syncthreads();
    if (tid < 8) {
        float lg = 0.f;
        for (int i = 0; i < 32; ++i) lg += pl[tid][i];
        red[tid] = lg;
    }
    __syncthreads();
    if (tid == 0) {
        int i0 = 0; float v0 = red[0];
        for (int k = 1; k < 8; ++k) if (red[k] > v0) { v0 = red[k]; i0 = k; }
        int i1 = -1; float v1 = -3.4e38f;
        for (int k = 0; k < 8; ++k) if (k != i0 && red[k] > v1) { v1 = red[k]; i1 = k; }
        const float g1 = __expf(v1 - v0);
        const float invs = 1.f / (1.f + g1);
        top_i[b * 2] = i0; top_i[b * 2 + 1] = i1;
        gates[b * 2] = invs; gates[b * 2 + 1] = g1 * invs;
    }
}

// ---------------------------------------------------------------- MoE row map
// Sorts the 128 sequences by their pass-k expert; emits per-row token gather
// map + gate, and per-128-row tile descriptors (each tile single-expert).
// ntiles <= 84 per pass (sum ceil(77*cnt_e/128) <= 77 + 8*(127/128) < 85).
__global__ __launch_bounds__(256)
void build_rowmap(const int* __restrict__ top_i, const float* __restrict__ gates,
                  int* __restrict__ tokmap, float* __restrict__ rowgate,
                  int4* __restrict__ tileinfo, int* __restrict__ ntiles)
{
    __shared__ int cnt[8];
    __shared__ int seqpos[128];
    const int tid = threadIdx.x;
    for (int pass = 0; pass < 2; ++pass) {
        if (tid < 8) cnt[tid] = 0;
        __syncthreads();
        if (tid < 128) atomicAdd(&cnt[top_i[tid * 2 + pass]], 1);
        __syncthreads();
        if (tid == 0) {
            int cur[8];
            int off = 0, nt = 0;
            for (int e = 0; e < 8; ++e) {
                cur[e] = off;
                const int len = 77 * cnt[e];
                for (int t = 0; t < len; t += 128) {
                    tileinfo[pass * 96 + nt] =
                        make_int4(off + t, (len - t) < 128 ? (len - t) : 128, e, 0);
                    ++nt;
                }
                off += len;
            }
            ntiles[pass] = nt;
            for (int b = 0; b < 128; ++b) {
                const int e = top_i[b * 2 + pass];
                seqpos[b] = cur[e];
                cur[e] += 77;
            }
        }
        __syncthreads();
        for (int c = tid; c < 9856; c += 256) {
            const int b = c / 77;
            const int dst = seqpos[b] + (c - b * 77);
            tokmap[pass * 9984 + dst] = c;          // token index b*77+s
            rowgate[pass * 9984 + dst] = gates[b * 2 + pass];
        }
        for (int c = tid; c < 128; c += 256) {      // gather-safe pads
            tokmap[pass * 9984 + 9856 + c] = 0;
            rowgate[pass * 9984 + 9856 + c] = 0.f;
        }
        __syncthreads();
    }
}

// ---------------------------------------------------------------- MFMA attention
// One block per (h,b). S padded 77->80 (M,N), PV k padded 77->96.
// LDS pool (64,768 B): Ks[80][64] | Vt[64][96] | Ss[80][84] f32 | X(Qs/Ps)
__global__ __launch_bounds__(256)
void attn_mfma(const __bf16* __restrict__ qkv, __bf16* __restrict__ ao)
{
    const int h = blockIdx.x, b = blockIdx.y;
    const int tid = threadIdx.x;
    __shared__ __align__(16) char pool[64768];
    __bf16 (*Ks)[64] = (__bf16(*)[64])pool;                 // 10,240
    __bf16 (*Vt)[96] = (__bf16(*)[96])(pool + 10240);       // 12,288
    float  (*Ss)[84] = (float (*)[84])(pool + 22528);       // 26,880
    __bf16 (*Qs)[64] = (__bf16(*)[64])(pool + 49408);       // 10,240 (aliases Ps)
    __bf16 (*Ps)[96] = (__bf16(*)[96])(pool + 49408);       // 15,360

    const size_t base = (size_t)b * SEQ * 3072 + (size_t)h * 64;

    // ---- load Q,K (8-elem vector chunks), V transposed, zero pads ----
    for (int c = tid; c < 77 * 8; c += 256) {
        const int s = c >> 3, d0 = (c & 7) << 3;
        *(bf16x8*)&Qs[s][d0] = *(const bf16x8*)&qkv[base + (size_t)s * 3072 + d0];
        *(bf16x8*)&Ks[s][d0] = *(const bf16x8*)&qkv[base + (size_t)s * 3072 + 1024 + d0];
    }
    for (int c = tid; c < 3 * 64; c += 256) {
        const int s = 77 + (c >> 6), d = c & 63;
        Qs[s][d] = (__bf16)0.f; Ks[s][d] = (__bf16)0.f;
    }
    for (int c = tid; c < 77 * 8; c += 256) {
        const int s = c >> 3, d0 = (c & 7) << 3;
        bf16x8 v = *(const bf16x8*)&qkv[base + (size_t)s * 3072 + 2048 + d0];
#pragma unroll
        for (int j = 0; j < 8; ++j) Vt[d0 + j][s] = v[j];
    }
    for (int c = tid; c < 64 * 19; c += 256) {
        const int d = c / 19, s = 77 + c % 19;
        Vt[d][s] = (__bf16)0.f;
    }
    __syncthreads();

    const int wv = tid >> 6, ln = tid & 63;
    const int fr = ln & 15, fq = ln >> 4;

    // ---- S = (Q K^T) * 0.125 : 25 fragment tiles round-robin over waves ----
    for (int f = wv; f < 25; f += 4) {
        const int mt = f / 5, nt = f - mt * 5;
        bf16x8 a0 = *(const bf16x8*)&Qs[mt * 16 + fr][fq * 8];
        bf16x8 a1 = *(const bf16x8*)&Qs[mt * 16 + fr][32 + fq * 8];
        bf16x8 b0 = *(const bf16x8*)&Ks[nt * 16 + fr][fq * 8];
        bf16x8 b1 = *(const bf16x8*)&Ks[nt * 16 + fr][32 + fq * 8];
        f32x4 acc = {0.f, 0.f, 0.f, 0.f};
        acc = __builtin_amdgcn_mfma_f32_16x16x32_bf16(a0, b0, acc, 0, 0, 0);
        acc = __builtin_amdgcn_mfma_f32_16x16x32_bf16(a1, b1, acc, 0, 0, 0);
#pragma unroll
        for (int r = 0; r < 4; ++r)
            Ss[mt * 16 + fq * 4 + r][nt * 16 + fr] = acc[r] * 0.125f;
    }
    __syncthreads();   // Qs dead from here; Ps may overwrite it

    // ---- softmax rows (cols 0..76 valid), P -> bf16 A-layout ----
    if (tid < 80) {
        float mx = -1e30f;
        for (int c = 0; c < 77; ++c) mx = fmaxf(mx, Ss[tid][c]);
        float sum = 0.f;
        for (int c = 0; c < 77; ++c) {
            const float e2 = __expf(Ss[tid][c] - mx);
            Ss[tid][c] = e2; sum += e2;
        }
        const float inv = 1.f / sum;
        for (int c = 0; c < 77; ++c) Ps[tid][c] = (__bf16)(Ss[tid][c] * inv);
        for (int c = 77; c < 96; ++c) Ps[tid][c] = (__bf16)0.f;
    }
    __syncthreads();

    // ---- O = P V : 20 fragment tiles, k = 96 (3 chunks) ----
    for (int f = wv; f < 20; f += 4) {
        const int mt = f >> 2, nt = f & 3;
        f32x4 acc = {0.f, 0.f, 0.f, 0.f};
#pragma unroll
        for (int kk = 0; kk < 3; ++kk) {
            bf16x8 a = *(const bf16x8*)&Ps[mt * 16 + fr][kk * 32 + fq * 8];
            bf16x8 bb = *(const bf16x8*)&Vt[nt * 16 + fr][kk * 32 + fq * 8];
            acc = __builtin_amdgcn_mfma_f32_16x16x32_bf16(a, bb, acc, 0, 0, 0);
        }
#pragma unroll
        for (int r = 0; r < 4; ++r) {
            const int m = mt * 16 + fq * 4 + r;
            if (m < 77)
                ao[((size_t)b * SEQ + m) * DMODEL + (size_t)h * 64 + nt * 16 + fr]
                    = (__bf16)acc[r];
        }
    }
}

// ---------------------------------------------------------------- weight prep
__global__ __launch_bounds__(256)
void cvt_kernel(const float* __restrict__ in, __bf16* __restrict__ out, int n4)
{
    const int i = blockIdx.x * 256 + threadIdx.x;
    if (i < n4) {
        const float4 v = ((const float4*)in)[i];
        bf16x4 o;
        o[0] = (__bf16)v.x; o[1] = (__bf16)v.y; o[2] = (__bf16)v.z; o[3] = (__bf16)v.w;
        ((bf16x4*)out)[i] = o;
    }
}

// in fp32 [R][C] (z<8: e_in + z*R*C, z==8: s_in) -> out bf16 [C][R]
__global__ __launch_bounds__(256)
void transpose_cvt(const float* __restrict__ e_in, const float* __restrict__ s_in,
                   __bf16* __restrict__ outw, int R, int C)
{
    const int z = blockIdx.z;
    const float* in = (z == 8) ? s_in : e_in + (size_t)z * R * C;
    __bf16* out = outw + (size_t)z * R * C;
    __shared__ float t[32][33];
    const int tr = threadIdx.x >> 3, tc4 = (threadIdx.x & 7) << 2;
    const int r0 = blockIdx.y << 5, c0 = blockIdx.x << 5;
    const float4 v = *(const float4*)&in[(size_t)(r0 + tr) * C + c0 + tc4];
    t[tr][tc4 + 0] = v.x; t[tr][tc4 + 1] = v.y;
    t[tr][tc4 + 2] = v.z; t[tr][tc4 + 3] = v.w;
    __syncthreads();
    bf16x4 o;
    o[0] = (__bf16)t[tc4 + 0][tr]; o[1] = (__bf16)t[tc4 + 1][tr];
    o[2] = (__bf16)t[tc4 + 2][tr]; o[3] = (__bf16)t[tc4 + 3][tr];
    *(bf16x4*)&out[(size_t)(c0 + tr) * R + r0 + tc4] = o;
}

// ---------------------------------------------------------------- GEMM (bf16 BT)
// m97 structure: 128x128 tile, BK=64, global_load_lds width-16 staging.
// A [M,K] bf16 row-major, Bw [N,K] bf16.
// EPI 0: bias->bf16  1: bias+relu->bf16  2: bias+resid->fp32  3: fp32 += bias+v
template<int EPI, bool MOE>
__global__ __launch_bounds__(256)
void gemm_bt(const __bf16* __restrict__ A, const __bf16* __restrict__ Bw,
             const float* __restrict__ bias, const float* __restrict__ resid,
             void* __restrict__ C, int N, int Kdim,
             const int* __restrict__ top_i, const float* __restrict__ gatesp,
             int pass, size_t bw_estride, int bias_estride)
{
    __shared__ __align__(16) __bf16 As[128][64];
    __shared__ __align__(16) __bf16 Bs[128][64];
    const int tid = threadIdx.x;
    int row0, valid;
    float gate = 1.f;
    if constexpr (MOE) {
        const int b = blockIdx.y;
        row0 = b * SEQ; valid = SEQ;
        const int e = top_i[b * 2 + pass];
        Bw += (size_t)e * bw_estride;
        bias += (size_t)e * (size_t)bias_estride;
        gate = gatesp[b * 2 + pass];
    } else { row0 = blockIdx.y * 128; valid = 128; }
    const int n0 = blockIdx.x * 128;

    const int wv = tid >> 6, ln = tid & 63;
    const int srow = wv * 32 + (ln >> 3), scol = (ln & 7) << 3;
    const __bf16* ag = A + (size_t)(row0 + srow) * Kdim + scol;
    const __bf16* bg = Bw + (size_t)(n0 + srow) * Kdim + scol;
    __bf16* asl = &As[0][0] + wv * 2048;   // wave-uniform LDS base
    __bf16* bsl = &Bs[0][0] + wv * 2048;

    const int fr = ln & 15, fq = ln >> 4;
    const int wm = (wv >> 1) << 6, wn = (wv & 1) << 6;

    f32x4 acc[4][4];
#pragma unroll
    for (int i = 0; i < 4; ++i)
#pragma unroll
        for (int j = 0; j < 4; ++j) acc[i][j] = f32x4{0.f, 0.f, 0.f, 0.f};

    for (int k0 = 0; k0 < Kdim; k0 += 64) {
        __syncthreads();                       // prior LDS reads complete
#pragma unroll
        for (int i = 0; i < 4; ++i) {
            gl16(ag + (size_t)i * 8 * Kdim, asl + i * 512);
            gl16(bg + (size_t)i * 8 * Kdim, bsl + i * 512);
        }
        ag += 64; bg += 64;
        __syncthreads();                       // vmcnt drain + barrier
        bf16x8 af[2][4], bf2[2][4];
#pragma unroll
        for (int kk = 0; kk < 2; ++kk) {
#pragma unroll
            for (int mm = 0; mm < 4; ++mm)
                af[kk][mm] = *(const bf16x8*)&As[wm + mm * 16 + fr][kk * 32 + fq * 8];
#pragma unroll
            for (int nn = 0; nn < 4; ++nn)
                bf2[kk][nn] = *(const bf16x8*)&Bs[wn + nn * 16 + fr][kk * 32 + fq * 8];
        }
#pragma unroll
        for (int mm = 0; mm < 4; ++mm)
#pragma unroll
            for (int nn = 0; nn < 4; ++nn) {
                acc[mm][nn] = __builtin_amdgcn_mfma_f32_16x16x32_bf16(
                    af[0][mm], bf2[0][nn], acc[mm][nn], 0, 0, 0);
                acc[mm][nn] = __builtin_amdgcn_mfma_f32_16x16x32_bf16(
                    af[1][mm], bf2[1][nn], acc[mm][nn], 0, 0, 0);
            }
    }

    float bv[4];
#pragma unroll
    for (int nn = 0; nn < 4; ++nn) bv[nn] = bias[n0 + wn + nn * 16 + fr];
#pragma unroll
    for (int mm = 0; mm < 4; ++mm) {
#pragma unroll
        for (int r = 0; r < 4; ++r) {
            const int m = wm + mm * 16 + (fq << 2) + r;
            if (!MOE || m < valid) {
                const size_t rowb = (size_t)(row0 + m) * N;
#pragma unroll
                for (int nn = 0; nn < 4; ++nn) {
                    const int n = n0 + wn + nn * 16 + fr;
                    float v = acc[mm][nn][r] + bv[nn];
                    if constexpr (EPI == 0) {
                        ((__bf16*)C)[rowb + n] = (__bf16)v;
                    } else if constexpr (EPI == 1) {
                        ((__bf16*)C)[rowb + n] = (__bf16)fmaxf(v, 0.f);
                    } else if constexpr (EPI == 2) {
                        ((float*)C)[rowb + n] = v + resid[rowb + n];
                    } else {
                        ((float*)C)[rowb + n] += gate * v;
                    }
                }
            }
        }
    }
}

// ---------------------------------------------------------------- MoE GEMM 1
// xn[tok] gathered via tokmap -> h (sorted rows, contiguous). K=1024, N=4096.
// Each tile is single-expert (from tileinfo). bias+relu -> bf16.
__global__ __launch_bounds__(256)
void gemm_moe1(const __bf16* __restrict__ A, const __bf16* __restrict__ w1T,
               const float* __restrict__ eb1, __bf16* __restrict__ h,
               const int* __restrict__ tokmap, const int4* __restrict__ tileinfo,
               const int* __restrict__ ntiles, int pass)
{
    const int tile = blockIdx.y;
    if (tile >= ntiles[pass]) return;
    __shared__ __align__(16) __bf16 As[128][64];
    __shared__ __align__(16) __bf16 Bs[128][64];
    const int4 ti = tileinfo[pass * 96 + tile];
    const int row0 = ti.x, valid = ti.y;
    const __bf16* Bw = w1T + (size_t)ti.z * 4194304;
    const float* bias = eb1 + (size_t)ti.z * 4096;
    const int n0 = blockIdx.x * 128;
    const int tid = threadIdx.x;
    const int wv = tid >> 6, ln = tid & 63;
    const int srow = wv * 32 + (ln >> 3), scol = (ln & 7) << 3;
    const int* tm = tokmap + pass * 9984 + row0 + srow;
    const __bf16* ag0 = A + (size_t)tm[0]  * 1024 + scol;
    const __bf16* ag1 = A + (size_t)tm[8]  * 1024 + scol;
    const __bf16* ag2 = A + (size_t)tm[16] * 1024 + scol;
    const __bf16* ag3 = A + (size_t)tm[24] * 1024 + scol;
    const __bf16* bg = Bw + (size_t)(n0 + srow) * 1024 + scol;
    __bf16* asl = &As[0][0] + wv * 2048;
    __bf16* bsl = &Bs[0][0] + wv * 2048;
    const int fr = ln & 15, fq = ln >> 4;
    const int wm = (wv >> 1) << 6, wn = (wv & 1) << 6;

    f32x4 acc[4][4];
#pragma unroll
    for (int i = 0; i < 4; ++i)
#pragma unroll
        for (int j = 0; j < 4; ++j) acc[i][j] = f32x4{0.f, 0.f, 0.f, 0.f};

    for (int k0 = 0; k0 < 1024; k0 += 64) {
        __syncthreads();
        gl16(ag0, asl);        gl16(ag1, asl + 512);
        gl16(ag2, asl + 1024); gl16(ag3, asl + 1536);
        gl16(bg,                      bsl);
        gl16(bg + (size_t) 8 * 1024,  bsl + 512);
        gl16(bg + (size_t)16 * 1024,  bsl + 1024);
        gl16(bg + (size_t)24 * 1024,  bsl + 1536);
        ag0 += 64; ag1 += 64; ag2 += 64; ag3 += 64; bg += 64;
        __syncthreads();
        bf16x8 af[2][4], bf2[2][4];
#pragma unroll
        for (int kk = 0; kk < 2; ++kk) {
#pragma unroll
            for (int mm = 0; mm < 4; ++mm)
                af[kk][mm] = *(const bf16x8*)&As[wm + mm * 16 + fr][kk * 32 + fq * 8];
#pragma unroll
            for (int nn = 0; nn < 4; ++nn)
                bf2[kk][nn] = *(const bf16x8*)&Bs[wn + nn * 16 + fr][kk * 32 + fq * 8];
        }
#pragma unroll
        for (int mm = 0; mm < 4; ++mm)
#pragma unroll
            for (int nn = 0; nn < 4; ++nn) {
                acc[mm][nn] = __builtin_amdgcn_mfma_f32_16x16x32_bf16(
                    af[0][mm], bf2[0][nn], acc[mm][nn], 0, 0, 0);
                acc[mm][nn] = __builtin_amdgcn_mfma_f32_16x16x32_bf16(
                    af[1][mm], bf2[1][nn], acc[mm][nn], 0, 0, 0);
            }
    }

    float bv[4];
#pragma unroll
    for (int nn = 0; nn < 4; ++nn) bv[nn] = bias[n0 + wn + nn * 16 + fr];
#pragma unroll
    for (int mm = 0; mm < 4; ++mm) {
#pragma unroll
        for (int r = 0; r < 4; ++r) {
            const int m = wm + mm * 16 + (fq << 2) + r;
            if (m < valid) {
                __bf16* hr = h + (size_t)(row0 + m) * 4096;
#pragma unroll
                for (int nn = 0; nn < 4; ++nn) {
                    const int n = n0 + wn + nn * 16 + fr;
                    hr[n] = (__bf16)fmaxf(acc[mm][nn][r] + bv[nn], 0.f);
                }
            }
        }
    }
}

// ---------------------------------------------------------------- split-K GEMM
// For the K=4096 -> N=1024 down-projections (MoE pass x2 + shared expert).
// grid (N/128, Mtiles, 4). Each z-block does a 1024-wide K-chunk, then
// fp32 atomicAdd into out (bias added by chunk 0 only).
// MOE: A rows sorted/contiguous (h), scatter rows via tokmap, scale rowgate.
// !MOE: identity rows, gate 1.
template<bool MOE>
__global__ __launch_bounds__(256)
void gemm_sk(const __bf16* __restrict__ A, const __bf16* __restrict__ Bw,
             const float* __restrict__ bias, float* __restrict__ out,
             int N, int Kdim,
             const int* __restrict__ tokmap, const float* __restrict__ rowgate,
             const int4* __restrict__ tileinfo, const int* __restrict__ ntiles,
             int pass)
{
    int row0, valid;
    if constexpr (MOE) {
        const int tile = blockIdx.y;
        if (tile >= ntiles[pass]) return;
        const int4 ti = tileinfo[pass * 96 + tile];
        row0 = ti.x; valid = ti.y;
        Bw += (size_t)ti.z * ((size_t)N * Kdim);
        bias += (size_t)ti.z * N;
    } else { row0 = blockIdx.y * 128; valid = 128; }
    __shared__ __align__(16) __bf16 As[128][64];
    __shared__ __align__(16) __bf16 Bs[128][64];
    const int n0 = blockIdx.x * 128;
    const int kz = blockIdx.z;
    const int kchunk = Kdim >> 2;              // SPLITK = 4
    const int koff = kz * kchunk;
    const int tid = threadIdx.x;
    const int wv = tid >> 6, ln = tid & 63;
    const int srow = wv * 32 + (ln >> 3), scol = (ln & 7) << 3;
    const __bf16* ag = A + (size_t)(row0 + srow) * Kdim + koff + scol;
    const __bf16* bg = Bw + (size_t)(n0 + srow) * Kdim + koff + scol;
    __bf16* asl = &As[0][0] + wv * 2048;
    __bf16* bsl = &Bs[0][0] + wv * 2048;
    const int fr = ln & 15, fq = ln >> 4;
    const int wm = (wv >> 1) << 6, wn = (wv & 1) << 6;

    f32x4 acc[4][4];
#pragma unroll
    for (int i = 0; i < 4; ++i)
#pragma unroll
        for (int j = 0; j < 4; ++j) acc[i][j] = f32x4{0.f, 0.f, 0.f, 0.f};

    for (int k0 = 0; k0 < kchunk; k0 += 64) {
        __syncthreads();
#pragma unroll
        for (int i = 0; i < 4; ++i) {
            gl16(ag + (size_t)i * 8 * Kdim, asl + i * 512);
            gl16(bg + (size_t)i * 8 * Kdim, bsl + i * 512);
        }
        ag += 64; bg += 64;
        __syncthreads();
        bf16x8 af[2][4], bf2[2][4];
#pragma unroll
        for (int kk = 0; kk < 2; ++kk) {
#pragma unroll
            for (int mm = 0; mm < 4; ++mm)
                af[kk][mm] = *(const bf16x8*)&As[wm + mm * 16 + fr][kk * 32 + fq * 8];
#pragma unroll
            for (int nn = 0; nn < 4; ++nn)
                bf2[kk][nn] = *(const bf16x8*)&Bs[wn + nn * 16 + fr][kk * 32 + fq * 8];
        }
#pragma unroll
        for (int mm = 0; mm < 4; ++mm)
#pragma unroll
            for (int nn = 0; nn < 4; ++nn) {
                acc[mm][nn] = __builtin_amdgcn_mfma_f32_16x16x32_bf16(
                    af[0][mm], bf2[0][nn], acc[mm][nn], 0, 0, 0);
                acc[mm][nn] = __builtin_amdgcn_mfma_f32_16x16x32_bf16(
                    af[1][mm], bf2[1][nn], acc[mm][nn], 0, 0, 0);
            }
    }

    float bv[4];
#pragma unroll
    for (int nn = 0; nn < 4; ++nn)
        bv[nn] = (kz == 0) ? bias[n0 + wn + nn * 16 + fr] : 0.f;
#pragma unroll
    for (int mm = 0; mm < 4; ++mm) {
#pragma unroll
        for (int r = 0; r < 4; ++r) {
            const int m = wm + mm * 16 + (fq << 2) + r;
            if (m < valid) {
                int dst; float g;
                if constexpr (MOE) {
                    dst = tokmap[pass * 9984 + row0 + m];
                    g = rowgate[pass * 9984 + row0 + m];
                } else { dst = row0 + m; g = 1.f; }
                float* orow = out + (size_t)dst * N;
#pragma unroll
                for (int nn = 0; nn < 4; ++nn) {
                    const int n = n0 + wn + nn * 16 + fr;
                    atomicAdd(&orow[n], g * (acc[mm][nn][r] + bv[nn]));
                }
            }
        }
    }
}

// ---------------------------------------------------------------- GEMM (round-1 fallback)
template<int BLAYOUT, int EPI, bool MOE>
__global__ __launch_bounds__(256)
void gemm_k(const __bf16* __restrict__ A, const float* __restrict__ Bw,
            const float* __restrict__ bias, const float* __restrict__ resid,
            void* __restrict__ C, int N, int Kdim,
            const int* __restrict__ top_i, const float* __restrict__ gatesp,
            int pass, size_t bw_estride, int bias_estride)
{
    __shared__ __align__(16) __bf16 As[128][40];
    __shared__ __align__(16) __bf16 Bs[128][40];
    const int tid = threadIdx.x;
    int row0, valid;
    float gate = 1.0f;
    if constexpr (MOE) {
        const int b = blockIdx.y;
        row0 = b * SEQ; valid = SEQ;
        const int e = top_i[b * 2 + pass];
        Bw += (size_t)e * bw_estride;
        bias += (size_t)e * (size_t)bias_estride;
        gate = gatesp[b * 2 + pass];
    } else { row0 = blockIdx.y * 128; valid = 128; }
    const int n0 = blockIdx.x * 128;
    const int ar = tid >> 1, ac = (tid & 1) << 4;
    const int bk = tid & 31, bg = tid >> 5;
    const int wave = tid >> 6, lane = tid & 63;
    const int wm = (wave >> 1) << 6, wn = (wave & 1) << 6;
    const int fr = lane & 15, fq = lane >> 4;
    f32x4 acc[4][4];
#pragma unroll
    for (int i = 0; i < 4; ++i)
#pragma unroll
        for (int j = 0; j < 4; ++j) acc[i][j] = f32x4{0.f, 0.f, 0.f, 0.f};
    const bool a_ok = (!MOE) || (ar < valid);
    const __bf16* aptr = A + (size_t)(row0 + ar) * Kdim + ac;
    for (int k0 = 0; k0 < Kdim; k0 += 32) {
        uint4 a0 = {0, 0, 0, 0}, a1 = {0, 0, 0, 0};
        if (a_ok) {
            const uint4* ap = (const uint4*)(aptr + k0);
            a0 = ap[0]; a1 = ap[1];
        }
        float4 f0, f1, f2, f3;
        if constexpr (BLAYOUT == 0) {
            const float4* bp = (const float4*)(Bw + (size_t)(n0 + ar) * Kdim + k0 + ac);
            f0 = bp[0]; f1 = bp[1]; f2 = bp[2]; f3 = bp[3];
        } else {
            const float4* bp = (const float4*)(Bw + (size_t)(k0 + bk) * N + n0 + (bg << 4));
            f0 = bp[0]; f1 = bp[1]; f2 = bp[2]; f3 = bp[3];
        }
        __syncthreads();
        *(uint4*)&As[ar][ac] = a0;
        *(uint4*)&As[ar][ac + 8] = a1;
        if constexpr (BLAYOUT == 0) {
            bf16x8 h0, h1;
            h0[0]=(__bf16)f0.x; h0[1]=(__bf16)f0.y; h0[2]=(__bf16)f0.z; h0[3]=(__bf16)f0.w;
            h0[4]=(__bf16)f1.x; h0[5]=(__bf16)f1.y; h0[6]=(__bf16)f1.z; h0[7]=(__bf16)f1.w;
            h1[0]=(__bf16)f2.x; h1[1]=(__bf16)f2.y; h1[2]=(__bf16)f2.z; h1[3]=(__bf16)f2.w;
            h1[4]=(__bf16)f3.x; h1[5]=(__bf16)f3.y; h1[6]=(__bf16)f3.z; h1[7]=(__bf16)f3.w;
            *(bf16x8*)&Bs[ar][ac] = h0;
            *(bf16x8*)&Bs[ar][ac + 8] = h1;
        } else {
            const int nb = bg << 4;
            Bs[nb + 0][bk] = (__bf16)f0.x;  Bs[nb + 1][bk] = (__bf16)f0.y;
            Bs[nb + 2][bk] = (__bf16)f0.z;  Bs[nb + 3][bk] = (__bf16)f0.w;
            Bs[nb + 4][bk] = (__bf16)f1.x;  Bs[nb + 5][bk] = (__bf16)f1.y;
            Bs[nb + 6][bk] = (__bf16)f1.z;  Bs[nb + 7][bk] = (__bf16)f1.w;
            Bs[nb + 8][bk] = (__bf16)f2.x;  Bs[nb + 9][bk] = (__bf16)f2.y;
            Bs[nb + 10][bk] = (__bf16)f2.z; Bs[nb + 11][bk] = (__bf16)f2.w;
            Bs[nb + 12][bk] = (__bf16)f3.x; Bs[nb + 13][bk] = (__bf16)f3.y;
            Bs[nb + 14][bk] = (__bf16)f3.z; Bs[nb + 15][bk] = (__bf16)f3.w;
        }
        __syncthreads();
        bf16x8 af[4], bfr[4];
#pragma unroll
        for (int mm = 0; mm < 4; ++mm)
            af[mm] = *(const bf16x8*)&As[wm + mm * 16 + fr][fq << 3];
#pragma unroll
        for (int nn = 0; nn < 4; ++nn)
            bfr[nn] = *(const bf16x8*)&Bs[wn + nn * 16 + fr][fq << 3];
#pragma unroll
        for (int mm = 0; mm < 4; ++mm)
#pragma unroll
            for (int nn = 0; nn < 4; ++nn)
                acc[mm][nn] = __builtin_amdgcn_mfma_f32_16x16x32_bf16(
                    af[mm], bfr[nn], acc[mm][nn], 0, 0, 0);
    }
    float bv[4];
#pragma unroll
    for (int nn = 0; nn < 4; ++nn) bv[nn] = bias[n0 + wn + nn * 16 + fr];
#pragma unroll
    for (int mm = 0; mm < 4; ++mm) {
#pragma unroll
        for (int r = 0; r < 4; ++r) {
            const int m = wm + mm * 16 + (fq << 2) + r;
            if (!MOE || m < valid) {
                const size_t rowb = (size_t)(row0 + m) * N;
#pragma unroll
                for (int nn = 0; nn < 4; ++nn) {
                    const int n = n0 + wn + nn * 16 + fr;
                    float v = acc[mm][nn][r] + bv[nn];
                    if constexpr (EPI == 0) {
                        ((__bf16*)C)[rowb + n] = (__bf16)v;
                    } else if constexpr (EPI == 1) {
                        ((__bf16*)C)[rowb + n] = (__bf16)fmaxf(v, 0.f);
                    } else if constexpr (EPI == 2) {
                        ((float*)C)[rowb + n] = v + resid[rowb + n];
                    } else {
                        ((float*)C)[rowb + n] += gate * v;
                    }
                }
            }
        }
    }
}

// ---------------------------------------------------------------- launch
extern "C" void kernel_launch(void* const* d_in, const int* in_sizes, int n_in,
                              void* d_out, int out_size, void* d_ws, size_t ws_size,
                              hipStream_t stream)
{
    (void)in_sizes; (void)n_in; (void)out_size;
    const float* src      = (const float*)d_in[0];
    const float* packed_w = (const float*)d_in[1];
    const float* packed_b = (const float*)d_in[2];
    const float* out_w    = (const float*)d_in[3];
    const float* out_b    = (const float*)d_in[4];
    const float* ln1_w    = (const float*)d_in[5];
    const float* ln1_b    = (const float*)d_in[6];
    const float* ln2_w    = (const float*)d_in[7];
    const float* ln2_b    = (const float*)d_in[8];
    const float* router_w = (const float*)d_in[9];
    const float* ew1      = (const float*)d_in[10];
    const float* eb1      = (const float*)d_in[11];
    const float* ew2      = (const float*)d_in[12];
    const float* eb2      = (const float*)d_in[13];
    const float* sw1      = (const float*)d_in[14];
    const float* sb1      = (const float*)d_in[15];
    const float* sw2      = (const float*)d_in[16];
    const float* sb2      = (const float*)d_in[17];
    float* out = (float*)d_out;
    char* ws = (char*)d_ws;

    const size_t FULL_NEED = 261621760;
    if (ws_size >= FULL_NEED) {
        __bf16* w1T  = (__bf16*)(ws);                   // [9][4096][1024]
        __bf16* w2T  = (__bf16*)(ws + 75497472);        // [9][1024][4096]
        __bf16* pwB  = (__bf16*)(ws + 150994944);       // [3072][1024]
        __bf16* owB  = (__bf16*)(ws + 157286400);       // [1024][1024]
        __bf16* xn   = (__bf16*)(ws + 159383552);       // [9856][1024]
        int*    tokmap   = (int*)(ws + 179568640);      // [2][9984]
        float*  rowgate  = (float*)(ws + 179648512);    // [2][9984]
        int4*   tileinfo = (int4*)(ws + 179728384);     // [2][96]
        int*    ntiles   = (int*)(ws + 179731456);      // [2]
        char*   big  = ws + 179830784;
        __bf16* qkv  = (__bf16*)big;
        __bf16* ao   = (__bf16*)(big + 60555264);
        __bf16* hws  = (__bf16*)big;                    // 9984 x 4096
        int*    top_i = (int*)(ws + 261619712);
        float*  gates = (float*)(ws + 261619712 + 1024);

        // weight prep
        cvt_kernel<<<3072, 256, 0, stream>>>(packed_w, pwB, 786432);
        cvt_kernel<<<1024, 256, 0, stream>>>(out_w, owB, 262144);
        transpose_cvt<<<dim3(128, 32, 9), 256, 0, stream>>>(ew1, sw1, w1T, 1024, 4096);
        transpose_cvt<<<dim3(32, 128, 9), 256, 0, stream>>>(ew2, sw2, w2T, 4096, 1024);
        // attention block
        ln_kernel<<<NTOK, 256, 0, stream>>>(src, ln1_w, ln1_b, xn);
        gemm_bt<0, false><<<dim3(24, 77), 256, 0, stream>>>(
            xn, pwB, packed_b, nullptr, qkv, 3072, 1024, nullptr, nullptr, 0, 0, 0);
        attn_mfma<<<dim3(16, 128), 256, 0, stream>>>(qkv, ao);
        gemm_bt<2, false><<<dim3(8, 77), 256, 0, stream>>>(
            ao, owB, out_b, src, out, 1024, 1024, nullptr, nullptr, 0, 0, 0);
        // MoE block
        ln_kernel<<<NTOK, 256, 0, stream>>>(out, ln2_w, ln2_b, xn);
        router_kernel<<<128, 256, 0, stream>>>(out, ln2_w, ln2_b, router_w, top_i, gates);
        build_rowmap<<<1, 256, 0, stream>>>(top_i, gates, tokmap, rowgate,
                                            tileinfo, ntiles);
        for (int pass = 0; pass < 2; ++pass) {
            gemm_moe1<<<dim3(32, 84), 256, 0, stream>>>(
                xn, w1T, eb1, hws, tokmap, tileinfo, ntiles, pass);
            gemm_sk<true><<<dim3(8, 84, 4), 256, 0, stream>>>(
                hws, w2T, eb2, out, 1024, 4096,
                tokmap, rowgate, tileinfo, ntiles, pass);
        }
        gemm_bt<1, false><<<dim3(32, 77), 256, 0, stream>>>(
            xn, w1T + (size_t)8 * 4194304, sb1, nullptr, hws, 4096, 1024,
            nullptr, nullptr, 0, 0, 0);
        gemm_sk<false><<<dim3(8, 77, 4), 256, 0, stream>>>(
            hws, w2T + (size_t)8 * 4194304, sb2, out, 1024, 4096,
            nullptr, nullptr, nullptr, nullptr, 0);
    } else {
        // -------- round-1 fallback (fp32 weights) with MFMA attention --------
        __bf16* xn   = (__bf16*)(ws);
        __bf16* qkv  = (__bf16*)(ws + 20185088);
        __bf16* ao   = (__bf16*)(ws + 80740352);
        __bf16* hws  = (__bf16*)(ws + 20185088);
        __bf16* ffn  = xn;
        int*    top_i = (int*)(ws + 100925440);
        float*  gates = (float*)(ws + 100925440 + 1024);

        ln_kernel<<<NTOK, 256, 0, stream>>>(src, ln1_w, ln1_b, xn);
        gemm_k<0, 0, false><<<dim3(24, 77), 256, 0, stream>>>(
            xn, packed_w, packed_b, nullptr, qkv, 3072, 1024,
            nullptr, nullptr, 0, 0, 0);
        attn_mfma<<<dim3(16, 128), 256, 0, stream>>>(qkv, ao);
        gemm_k<0, 2, false><<<dim3(8, 77), 256, 0, stream>>>(
            ao, out_w, out_b, src, out, 1024, 1024,
            nullptr, nullptr, 0, 0, 0);
        ln_kernel<<<NTOK, 256, 0, stream>>>(out, ln2_w, ln2_b, ffn);
        router_kernel<<<128, 256, 0, stream>>>(out, ln2_w, ln2_b, router_w, top_i, gates);
        for (int pass = 0; pass < 2; ++pass) {
            gemm_k<1, 1, true><<<dim3(32, 128), 256, 0, stream>>>(
                ffn, ew1, eb1, nullptr, hws, 4096, 1024,
                top_i, gates, pass, (size_t)1024 * 4096, 4096);
            gemm_k<1, 3, true><<<dim3(8, 128), 256, 0, stream>>>(
                hws, ew2, eb2, nullptr, out, 1024, 4096,
                top_i, gates, pass, (size_t)4096 * 1024, 1024);
        }
        gemm_k<1, 1, false><<<dim3(32, 77), 256, 0, stream>>>(
            ffn, sw1, sb1, nullptr, hws, 4096, 1024,
            nullptr, nullptr, 0, 0, 0);
        gemm_k<1, 3, false><<<dim3(8, 77), 256, 0, stream>>>(
            hws, sw2, sb2, nullptr, out, 1024, 4096,
            nullptr, nullptr, 0, 0, 0);
    }
}

// Round 3
// 1681.353 us; speedup vs baseline: 1.0475x; 1.0475x over previous
//
#include <hip/hip_runtime.h>

// MyTransformerEncoderLayer: B=128,S=77,D=1024,H=16,DH=64,F=4096,E=8,topK=2
// Round 5: attack the two measured pathologies in all m97-style GEMMs:
//  (a) 16-way LDS bank conflicts on ds_read_b128 (SQ_LDS_BANK_CONFLICT=3.2e7
//      = 21% of CU-cycles) -> both-sides XOR swizzle: linear global_load_lds
//      dest + pre-swizzled global source col + swizzled read col.
//  (b) serial vmcnt(0) drain every K-step -> minimum 2-phase pipeline:
//      double-buffered LDS (64KB), stage next tile BEFORE compute of current,
//      one raw s_barrier + vmcnt(0) per K-step (guide T3 minimal recipe).
// Expert-sorted MoE + split-K=4 down-proj + MFMA attention kept from R3/R4.
//
// ws layout unchanged, FULL_NEED = 261,621,760.

typedef float f32x4 __attribute__((ext_vector_type(4)));
typedef __bf16 bf16x8 __attribute__((ext_vector_type(8)));
typedef __bf16 bf16x4 __attribute__((ext_vector_type(4)));

#define NTOK 9856
#define DMODEL 1024
#define SEQ 77

__device__ __forceinline__ void gl16(const __bf16* g, __bf16* l) {
    __builtin_amdgcn_global_load_lds(
        (const __attribute__((address_space(1))) unsigned int*)g,
        (__attribute__((address_space(3))) unsigned int*)l, 16, 0, 0);
}

// ---------------------------------------------------------------- LayerNorm
__global__ __launch_bounds__(256)
void ln_kernel(const float* __restrict__ x, const float* __restrict__ w,
               const float* __restrict__ bb, __bf16* __restrict__ out)
{
    const int t = blockIdx.x, tid = threadIdx.x;
    const float4 v = ((const float4*)(x + (size_t)t * DMODEL))[tid];
    float s = v.x + v.y + v.z + v.w;
    float q = v.x*v.x + v.y*v.y + v.z*v.z + v.w*v.w;
#pragma unroll
    for (int off = 32; off; off >>= 1) {
        s += __shfl_xor(s, off, 64);
        q += __shfl_xor(q, off, 64);
    }
    __shared__ float rs[4], rq[4];
    const int wv = tid >> 6, lane = tid & 63;
    if (lane == 0) { rs[wv] = s; rq[wv] = q; }
    __syncthreads();
    s = rs[0] + rs[1] + rs[2] + rs[3];
    q = rq[0] + rq[1] + rq[2] + rq[3];
    const float mean = s * (1.f / 1024.f);
    const float rstd = rsqrtf(q * (1.f / 1024.f) - mean * mean + 1e-5f);
    const float4 wv4 = ((const float4*)w)[tid];
    const float4 bv4 = ((const float4*)bb)[tid];
    bf16x4 o;
    o[0] = (__bf16)((v.x - mean) * rstd * wv4.x + bv4.x);
    o[1] = (__bf16)((v.y - mean) * rstd * wv4.y + bv4.y);
    o[2] = (__bf16)((v.z - mean) * rstd * wv4.z + bv4.z);
    o[3] = (__bf16)((v.w - mean) * rstd * wv4.w + bv4.w);
    ((bf16x4*)out)[(size_t)t * 256 + tid] = o;
}

// ---------------------------------------------------------------- Router
__global__ __launch_bounds__(256)
void router_kernel(const float* __restrict__ x, const float* __restrict__ w,
                   const float* __restrict__ bb, const float* __restrict__ rw,
                   int* __restrict__ top_i, float* __restrict__ gates)
{
    const int b = blockIdx.x, tid = threadIdx.x;
    __shared__ float lnv[1024];
    __shared__ float red[8];
    __shared__ float pl[8][33];
    const float4 v = ((const float4*)(x + (size_t)b * SEQ * DMODEL))[tid];
    float s = v.x + v.y + v.z + v.w;
    float q = v.x*v.x + v.y*v.y + v.z*v.z + v.w*v.w;
#pragma unroll
    for (int off = 32; off; off >>= 1) {
        s += __shfl_xor(s, off, 64);
        q += __shfl_xor(q, off, 64);
    }
    const int wv = tid >> 6, lane = tid & 63;
    if (lane == 0) { red[wv] = s; red[4 + wv] = q; }
    __syncthreads();
    s = red[0] + red[1] + red[2] + red[3];
    q = red[4] + red[5] + red[6] + red[7];
    const float mean = s * (1.f / 1024.f);
    const float rstd = rsqrtf(q * (1.f / 1024.f) - mean * mean + 1e-5f);
    const float4 wv4 = ((const float4*)w)[tid];
    const float4 bv4 = ((const float4*)bb)[tid];
    lnv[4 * tid + 0] = (v.x - mean) * rstd * wv4.x + bv4.x;
    lnv[4 * tid + 1] = (v.y - mean) * rstd * wv4.y + bv4.y;
    lnv[4 * tid + 2] = (v.z - mean) * rstd * wv4.z + bv4.z;
    lnv[4 * tid + 3] = (v.w - mean) * rstd * wv4.w + bv4.w;
    __syncthreads();
    const int e = tid >> 5, g = tid & 31;
    float p = 0.f;
    for (int d = g; d < 1024; d += 32) p += lnv[d] * rw[(size_t)e * 1024 + d];
    pl[e][g] = p;
    __syncthreads();
    if (tid < 8) {
        float lg = 0.f;
        for (int i = 0; i < 32; ++i) lg += pl[tid][i];
        red[tid] = lg;
    }
    __syncthreads();
    if (tid == 0) {
        int i0 = 0; float v0 = red[0];
        for (int k = 1; k < 8; ++k) if (red[k] > v0) { v0 = red[k]; i0 = k; }
        int i1 = -1; float v1 = -3.4e38f;
        for (int k = 0; k < 8; ++k) if (k != i0 && red[k] > v1) { v1 = red[k]; i1 = k; }
        const float g1 = __expf(v1 - v0);
        const float invs = 1.f / (1.f + g1);
        top_i[b * 2] = i0; top_i[b * 2 + 1] = i1;
        gates[b * 2] = invs; gates[b * 2 + 1] = g1 * invs;
    }
}

// ---------------------------------------------------------------- MoE row map
__global__ __launch_bounds__(256)
void build_rowmap(const int* __restrict__ top_i, const float* __restrict__ gates,
                  int* __restrict__ tokmap, float* __restrict__ rowgate,
                  int4* __restrict__ tileinfo, int* __restrict__ ntiles)
{
    __shared__ int cnt[8];
    __shared__ int seqpos[128];
    const int tid = threadIdx.x;
    for (int pass = 0; pass < 2; ++pass) {
        if (tid < 8) cnt[tid] = 0;
        __syncthreads();
        if (tid < 128) atomicAdd(&cnt[top_i[tid * 2 + pass]], 1);
        __syncthreads();
        if (tid == 0) {
            int cur[8];
            int off = 0, nt = 0;
            for (int e = 0; e < 8; ++e) {
                cur[e] = off;
                const int len = 77 * cnt[e];
                for (int t = 0; t < len; t += 128) {
                    tileinfo[pass * 96 + nt] =
                        make_int4(off + t, (len - t) < 128 ? (len - t) : 128, e, 0);
                    ++nt;
                }
                off += len;
            }
            ntiles[pass] = nt;
            for (int b = 0; b < 128; ++b) {
                const int e = top_i[b * 2 + pass];
                seqpos[b] = cur[e];
                cur[e] += 77;
            }
        }
        __syncthreads();
        for (int c = tid; c < 9856; c += 256) {
            const int b = c / 77;
            const int dst = seqpos[b] + (c - b * 77);
            tokmap[pass * 9984 + dst] = c;
            rowgate[pass * 9984 + dst] = gates[b * 2 + pass];
        }
        for (int c = tid; c < 128; c += 256) {
            tokmap[pass * 9984 + 9856 + c] = 0;
            rowgate[pass * 9984 + 9856 + c] = 0.f;
        }
        __syncthreads();
    }
}

// ---------------------------------------------------------------- MFMA attention
__global__ __launch_bounds__(256)
void attn_mfma(const __bf16* __restrict__ qkv, __bf16* __restrict__ ao)
{
    const int h = blockIdx.x, b = blockIdx.y;
    const int tid = threadIdx.x;
    __shared__ __align__(16) char pool[64768];
    __bf16 (*Ks)[64] = (__bf16(*)[64])pool;
    __bf16 (*Vt)[96] = (__bf16(*)[96])(pool + 10240);
    float  (*Ss)[84] = (float (*)[84])(pool + 22528);
    __bf16 (*Qs)[64] = (__bf16(*)[64])(pool + 49408);
    __bf16 (*Ps)[96] = (__bf16(*)[96])(pool + 49408);

    const size_t base = (size_t)b * SEQ * 3072 + (size_t)h * 64;

    for (int c = tid; c < 77 * 8; c += 256) {
        const int s = c >> 3, d0 = (c & 7) << 3;
        *(bf16x8*)&Qs[s][d0] = *(const bf16x8*)&qkv[base + (size_t)s * 3072 + d0];
        *(bf16x8*)&Ks[s][d0] = *(const bf16x8*)&qkv[base + (size_t)s * 3072 + 1024 + d0];
    }
    for (int c = tid; c < 3 * 64; c += 256) {
        const int s = 77 + (c >> 6), d = c & 63;
        Qs[s][d] = (__bf16)0.f; Ks[s][d] = (__bf16)0.f;
    }
    for (int c = tid; c < 77 * 8; c += 256) {
        const int s = c >> 3, d0 = (c & 7) << 3;
        bf16x8 v = *(const bf16x8*)&qkv[base + (size_t)s * 3072 + 2048 + d0];
#pragma unroll
        for (int j = 0; j < 8; ++j) Vt[d0 + j][s] = v[j];
    }
    for (int c = tid; c < 64 * 19; c += 256) {
        const int d = c / 19, s = 77 + c % 19;
        Vt[d][s] = (__bf16)0.f;
    }
    __syncthreads();

    const int wv = tid >> 6, ln = tid & 63;
    const int fr = ln & 15, fq = ln >> 4;

    for (int f = wv; f < 25; f += 4) {
        const int mt = f / 5, nt = f - mt * 5;
        bf16x8 a0 = *(const bf16x8*)&Qs[mt * 16 + fr][fq * 8];
        bf16x8 a1 = *(const bf16x8*)&Qs[mt * 16 + fr][32 + fq * 8];
        bf16x8 b0 = *(const bf16x8*)&Ks[nt * 16 + fr][fq * 8];
        bf16x8 b1 = *(const bf16x8*)&Ks[nt * 16 + fr][32 + fq * 8];
        f32x4 acc = {0.f, 0.f, 0.f, 0.f};
        acc = __builtin_amdgcn_mfma_f32_16x16x32_bf16(a0, b0, acc, 0, 0, 0);
        acc = __builtin_amdgcn_mfma_f32_16x16x32_bf16(a1, b1, acc, 0, 0, 0);
#pragma unroll
        for (int r = 0; r < 4; ++r)
            Ss[mt * 16 + fq * 4 + r][nt * 16 + fr] = acc[r] * 0.125f;
    }
    __syncthreads();

    if (tid < 80) {
        float mx = -1e30f;
        for (int c = 0; c < 77; ++c) mx = fmaxf(mx, Ss[tid][c]);
        float sum = 0.f;
        for (int c = 0; c < 77; ++c) {
            const float e2 = __expf(Ss[tid][c] - mx);
            Ss[tid][c] = e2; sum += e2;
        }
        const float inv = 1.f / sum;
        for (int c = 0; c < 77; ++c) Ps[tid][c] = (__bf16)(Ss[tid][c] * inv);
        for (int c = 77; c < 96; ++c) Ps[tid][c] = (__bf16)0.f;
    }
    __syncthreads();

    for (int f = wv; f < 20; f += 4) {
        const int mt = f >> 2, nt = f & 3;
        f32x4 acc = {0.f, 0.f, 0.f, 0.f};
#pragma unroll
        for (int kk = 0; kk < 3; ++kk) {
            bf16x8 a = *(const bf16x8*)&Ps[mt * 16 + fr][kk * 32 + fq * 8];
            bf16x8 bb = *(const bf16x8*)&Vt[nt * 16 + fr][kk * 32 + fq * 8];
            acc = __builtin_amdgcn_mfma_f32_16x16x32_bf16(a, bb, acc, 0, 0, 0);
        }
#pragma unroll
        for (int r = 0; r < 4; ++r) {
            const int m = mt * 16 + fq * 4 + r;
            if (m < 77)
                ao[((size_t)b * SEQ + m) * DMODEL + (size_t)h * 64 + nt * 16 + fr]
                    = (__bf16)acc[r];
        }
    }
}

// ---------------------------------------------------------------- weight prep
__global__ __launch_bounds__(256)
void cvt_kernel(const float* __restrict__ in, __bf16* __restrict__ out, int n4)
{
    const int i = blockIdx.x * 256 + threadIdx.x;
    if (i < n4) {
        const float4 v = ((const float4*)in)[i];
        bf16x4 o;
        o[0] = (__bf16)v.x; o[1] = (__bf16)v.y; o[2] = (__bf16)v.z; o[3] = (__bf16)v.w;
        ((bf16x4*)out)[i] = o;
    }
}

__global__ __launch_bounds__(256)
void transpose_cvt(const float* __restrict__ e_in, const float* __restrict__ s_in,
                   __bf16* __restrict__ outw, int R, int C)
{
    const int z = blockIdx.z;
    const float* in = (z == 8) ? s_in : e_in + (size_t)z * R * C;
    __bf16* out = outw + (size_t)z * R * C;
    __shared__ float t[32][33];
    const int tr = threadIdx.x >> 3, tc4 = (threadIdx.x & 7) << 2;
    const int r0 = blockIdx.y << 5, c0 = blockIdx.x << 5;
    const float4 v = *(const float4*)&in[(size_t)(r0 + tr) * C + c0 + tc4];
    t[tr][tc4 + 0] = v.x; t[tr][tc4 + 1] = v.y;
    t[tr][tc4 + 2] = v.z; t[tr][tc4 + 3] = v.w;
    __syncthreads();
    bf16x4 o;
    o[0] = (__bf16)t[tc4 + 0][tr]; o[1] = (__bf16)t[tc4 + 1][tr];
    o[2] = (__bf16)t[tc4 + 2][tr]; o[3] = (__bf16)t[tc4 + 3][tr];
    *(bf16x4*)&out[(size_t)(c0 + tr) * R + r0 + tc4] = o;
}

// ============================================================================
// Shared pieces for the pipelined swizzled GEMMs.
// LDS element (row, 16B-slot c) holds logical slot c ^ (row&7).
// Staging: linear gl16 dest; source col pre-swizzled: ((ln&7)^((ln>>3)&7))<<3.
// Read: logical slot kk*4+fq at row (..+fr) -> physical ((kk*4+fq)^(fr&7))<<3.
// ============================================================================

#define GEMM_COMPUTE(AS, BS)                                                   \
    {                                                                          \
        bf16x8 af[2][4], bf2[2][4];                                            \
        _Pragma("unroll")                                                      \
        for (int mm = 0; mm < 4; ++mm) {                                       \
            const int rw = wm + mm * 16 + fr;                                  \
            af[0][mm] = *(const bf16x8*)&AS[rw][rc0];                          \
            af[1][mm] = *(const bf16x8*)&AS[rw][rc1];                          \
        }                                                                      \
        _Pragma("unroll")                                                      \
        for (int nn = 0; nn < 4; ++nn) {                                       \
            const int rw = wn + nn * 16 + fr;                                  \
            bf2[0][nn] = *(const bf16x8*)&BS[rw][rc0];                         \
            bf2[1][nn] = *(const bf16x8*)&BS[rw][rc1];                         \
        }                                                                      \
        _Pragma("unroll")                                                      \
        for (int mm = 0; mm < 4; ++mm)                                         \
            _Pragma("unroll")                                                  \
            for (int nn = 0; nn < 4; ++nn) {                                   \
                acc[mm][nn] = __builtin_amdgcn_mfma_f32_16x16x32_bf16(         \
                    af[0][mm], bf2[0][nn], acc[mm][nn], 0, 0, 0);              \
                acc[mm][nn] = __builtin_amdgcn_mfma_f32_16x16x32_bf16(         \
                    af[1][mm], bf2[1][nn], acc[mm][nn], 0, 0, 0);              \
            }                                                                  \
    }

// ---------------------------------------------------------------- GEMM (bf16 BT)
// 128x128 tile, BK=64, double-buffered LDS (64KB), 2-phase pipeline.
// EPI 0: bias->bf16  1: bias+relu->bf16  2: bias+resid->fp32  3: fp32 += bias+v
template<int EPI, bool MOE>
__global__ __launch_bounds__(256)
void gemm_bt(const __bf16* __restrict__ A, const __bf16* __restrict__ Bw,
             const float* __restrict__ bias, const float* __restrict__ resid,
             void* __restrict__ C, int N, int Kdim,
             const int* __restrict__ top_i, const float* __restrict__ gatesp,
             int pass, size_t bw_estride, int bias_estride)
{
    __shared__ __align__(16) __bf16 As[2][128][64];
    __shared__ __align__(16) __bf16 Bs[2][128][64];
    const int tid = threadIdx.x;
    int row0, valid;
    float gate = 1.f;
    if constexpr (MOE) {
        const int b = blockIdx.y;
        row0 = b * SEQ; valid = SEQ;
        const int e = top_i[b * 2 + pass];
        Bw += (size_t)e * bw_estride;
        bias += (size_t)e * (size_t)bias_estride;
        gate = gatesp[b * 2 + pass];
    } else { row0 = blockIdx.y * 128; valid = 128; }
    const int n0 = blockIdx.x * 128;

    const int wv = tid >> 6, ln = tid & 63;
    const int srow = wv * 32 + (ln >> 3);
    const int scol = (((ln & 7) ^ ((ln >> 3) & 7)) << 3);   // pre-swizzled src
    const __bf16* ag = A + (size_t)(row0 + srow) * Kdim + scol;
    const __bf16* bg = Bw + (size_t)(n0 + srow) * Kdim + scol;

    const int fr = ln & 15, fq = ln >> 4;
    const int wm = (wv >> 1) << 6, wn = (wv & 1) << 6;
    const int rc0 = ((fq ^ (fr & 7)) << 3);
    const int rc1 = rc0 ^ 32;

    f32x4 acc[4][4];
#pragma unroll
    for (int i = 0; i < 4; ++i)
#pragma unroll
        for (int j = 0; j < 4; ++j) acc[i][j] = f32x4{0.f, 0.f, 0.f, 0.f};

#define STAGE_BT(buf)                                                          \
    {                                                                          \
        __bf16* asl = &As[buf][0][0] + wv * 2048;                              \
        __bf16* bsl = &Bs[buf][0][0] + wv * 2048;                              \
        gl16(ag,                       asl);                                   \
        gl16(ag + (size_t) 8 * Kdim,   asl + 512);                             \
        gl16(ag + (size_t)16 * Kdim,   asl + 1024);                            \
        gl16(ag + (size_t)24 * Kdim,   asl + 1536);                            \
        gl16(bg,                       bsl);                                   \
        gl16(bg + (size_t) 8 * Kdim,   bsl + 512);                             \
        gl16(bg + (size_t)16 * Kdim,   bsl + 1024);                            \
        gl16(bg + (size_t)24 * Kdim,   bsl + 1536);                            \
        ag += 64; bg += 64;                                                    \
    }

    const int nk = Kdim >> 6;
    STAGE_BT(0);
    asm volatile("s_waitcnt vmcnt(0)" ::: "memory");
    __builtin_amdgcn_s_barrier();
    for (int kt = 0; kt < nk; ++kt) {
        const int cur = kt & 1;
        if (kt + 1 < nk) STAGE_BT(cur ^ 1);
        GEMM_COMPUTE(As[cur], Bs[cur]);
        if (kt + 1 < nk) {
            asm volatile("s_waitcnt vmcnt(0)" ::: "memory");
            __builtin_amdgcn_s_barrier();
        }
    }
#undef STAGE_BT

    float bv[4];
#pragma unroll
    for (int nn = 0; nn < 4; ++nn) bv[nn] = bias[n0 + wn + nn * 16 + fr];
#pragma unroll
    for (int mm = 0; mm < 4; ++mm) {
#pragma unroll
        for (int r = 0; r < 4; ++r) {
            const int m = wm + mm * 16 + (fq << 2) + r;
            if (!MOE || m < valid) {
                const size_t rowb = (size_t)(row0 + m) * N;
#pragma unroll
                for (int nn = 0; nn < 4; ++nn) {
                    const int n = n0 + wn + nn * 16 + fr;
                    float v = acc[mm][nn][r] + bv[nn];
                    if constexpr (EPI == 0) {
                        ((__bf16*)C)[rowb + n] = (__bf16)v;
                    } else if constexpr (EPI == 1) {
                        ((__bf16*)C)[rowb + n] = (__bf16)fmaxf(v, 0.f);
                    } else if constexpr (EPI == 2) {
                        ((float*)C)[rowb + n] = v + resid[rowb + n];
                    } else {
                        ((float*)C)[rowb + n] += gate * v;
                    }
                }
            }
        }
    }
}

// ---------------------------------------------------------------- MoE GEMM 1
// xn gathered via tokmap -> h (sorted rows). K=1024, N=4096. bias+relu.
__global__ __launch_bounds__(256)
void gemm_moe1(const __bf16* __restrict__ A, const __bf16* __restrict__ w1T,
               const float* __restrict__ eb1, __bf16* __restrict__ h,
               const int* __restrict__ tokmap, const int4* __restrict__ tileinfo,
               const int* __restrict__ ntiles, int pass)
{
    const int tile = blockIdx.y;
    if (tile >= ntiles[pass]) return;
    __shared__ __align__(16) __bf16 As[2][128][64];
    __shared__ __align__(16) __bf16 Bs[2][128][64];
    const int4 ti = tileinfo[pass * 96 + tile];
    const int row0 = ti.x, valid = ti.y;
    const __bf16* Bw = w1T + (size_t)ti.z * 4194304;
    const float* bias = eb1 + (size_t)ti.z * 4096;
    const int n0 = blockIdx.x * 128;
    const int tid = threadIdx.x;
    const int wv = tid >> 6, ln = tid & 63;
    const int srow = wv * 32 + (ln >> 3);
    const int scol = (((ln & 7) ^ ((ln >> 3) & 7)) << 3);
    const int* tm = tokmap + pass * 9984 + row0 + srow;
    const __bf16* ag0 = A + (size_t)tm[0]  * 1024 + scol;
    const __bf16* ag1 = A + (size_t)tm[8]  * 1024 + scol;
    const __bf16* ag2 = A + (size_t)tm[16] * 1024 + scol;
    const __bf16* ag3 = A + (size_t)tm[24] * 1024 + scol;
    const __bf16* bg = Bw + (size_t)(n0 + srow) * 1024 + scol;
    const int fr = ln & 15, fq = ln >> 4;
    const int wm = (wv >> 1) << 6, wn = (wv & 1) << 6;
    const int rc0 = ((fq ^ (fr & 7)) << 3);
    const int rc1 = rc0 ^ 32;

    f32x4 acc[4][4];
#pragma unroll
    for (int i = 0; i < 4; ++i)
#pragma unroll
        for (int j = 0; j < 4; ++j) acc[i][j] = f32x4{0.f, 0.f, 0.f, 0.f};

#define STAGE_M1(buf)                                                          \
    {                                                                          \
        __bf16* asl = &As[buf][0][0] + wv * 2048;                              \
        __bf16* bsl = &Bs[buf][0][0] + wv * 2048;                              \
        gl16(ag0, asl);        gl16(ag1, asl + 512);                           \
        gl16(ag2, asl + 1024); gl16(ag3, asl + 1536);                          \
        gl16(bg,         bsl);        gl16(bg +  8192, bsl + 512);             \
        gl16(bg + 16384, bsl + 1024); gl16(bg + 24576, bsl + 1536);            \
        ag0 += 64; ag1 += 64; ag2 += 64; ag3 += 64; bg += 64;                  \
    }

    STAGE_M1(0);
    asm volatile("s_waitcnt vmcnt(0)" ::: "memory");
    __builtin_amdgcn_s_barrier();
    for (int kt = 0; kt < 16; ++kt) {
        const int cur = kt & 1;
        if (kt + 1 < 16) STAGE_M1(cur ^ 1);
        GEMM_COMPUTE(As[cur], Bs[cur]);
        if (kt + 1 < 16) {
            asm volatile("s_waitcnt vmcnt(0)" ::: "memory");
            __builtin_amdgcn_s_barrier();
        }
    }
#undef STAGE_M1

    float bv[4];
#pragma unroll
    for (int nn = 0; nn < 4; ++nn) bv[nn] = bias[n0 + wn + nn * 16 + fr];
#pragma unroll
    for (int mm = 0; mm < 4; ++mm) {
#pragma unroll
        for (int r = 0; r < 4; ++r) {
            const int m = wm + mm * 16 + (fq << 2) + r;
            if (m < valid) {
                __bf16* hr = h + (size_t)(row0 + m) * 4096;
#pragma unroll
                for (int nn = 0; nn < 4; ++nn) {
                    const int n = n0 + wn + nn * 16 + fr;
                    hr[n] = (__bf16)fmaxf(acc[mm][nn][r] + bv[nn], 0.f);
                }
            }
        }
    }
}

// ---------------------------------------------------------------- split-K GEMM
// K=4096 -> N=1024 down-projections. grid (8, Mtiles, 4). fp32 atomicAdd,
// bias added by kz==0 only.
template<bool MOE>
__global__ __launch_bounds__(256)
void gemm_sk(const __bf16* __restrict__ A, const __bf16* __restrict__ Bw,
             const float* __restrict__ bias, float* __restrict__ out,
             int N, int Kdim,
             const int* __restrict__ tokmap, const float* __restrict__ rowgate,
             const int4* __restrict__ tileinfo, const int* __restrict__ ntiles,
             int pass)
{
    int row0, valid;
    if constexpr (MOE) {
        const int tile = blockIdx.y;
        if (tile >= ntiles[pass]) return;
        const int4 ti = tileinfo[pass * 96 + tile];
        row0 = ti.x; valid = ti.y;
        Bw += (size_t)ti.z * ((size_t)N * Kdim);
        bias += (size_t)ti.z * N;
    } else { row0 = blockIdx.y * 128; valid = 128; }
    __shared__ __align__(16) __bf16 As[2][128][64];
    __shared__ __align__(16) __bf16 Bs[2][128][64];
    const int n0 = blockIdx.x * 128;
    const int kz = blockIdx.z;
    const int kchunk = Kdim >> 2;              // SPLITK = 4
    const int koff = kz * kchunk;
    const int tid = threadIdx.x;
    const int wv = tid >> 6, ln = tid & 63;
    const int srow = wv * 32 + (ln >> 3);
    const int scol = (((ln & 7) ^ ((ln >> 3) & 7)) << 3);
    const __bf16* ag = A + (size_t)(row0 + srow) * Kdim + koff + scol;
    const __bf16* bg = Bw + (size_t)(n0 + srow) * Kdim + koff + scol;
    const int fr = ln & 15, fq = ln >> 4;
    const int wm = (wv >> 1) << 6, wn = (wv & 1) << 6;
    const int rc0 = ((fq ^ (fr & 7)) << 3);
    const int rc1 = rc0 ^ 32;

    f32x4 acc[4][4];
#pragma unroll
    for (int i = 0; i < 4; ++i)
#pragma unroll
        for (int j = 0; j < 4; ++j) acc[i][j] = f32x4{0.f, 0.f, 0.f, 0.f};

#define STAGE_SK(buf)                                                          \
    {                                                                          \
        __bf16* asl = &As[buf][0][0] + wv * 2048;                              \
        __bf16* bsl = &Bs[buf][0][0] + wv * 2048;                              \
        gl16(ag,                       asl);                                   \
        gl16(ag + (size_t) 8 * Kdim,   asl + 512);                             \
        gl16(ag + (size_t)16 * Kdim,   asl + 1024);                            \
        gl16(ag + (size_t)24 * Kdim,   asl + 1536);                            \
        gl16(bg,                       bsl);                                   \
        gl16(bg + (size_t) 8 * Kdim,   bsl + 512);                             \
        gl16(bg + (size_t)16 * Kdim,   bsl + 1024);                            \
        gl16(bg + (size_t)24 * Kdim,   bsl + 1536);                            \
        ag += 64; bg += 64;                                                    \
    }

    const int nk = kchunk >> 6;
    STAGE_SK(0);
    asm volatile("s_waitcnt vmcnt(0)" ::: "memory");
    __builtin_amdgcn_s_barrier();
    for (int kt = 0; kt < nk; ++kt) {
        const int cur = kt & 1;
        if (kt + 1 < nk) STAGE_SK(cur ^ 1);
        GEMM_COMPUTE(As[cur], Bs[cur]);
        if (kt + 1 < nk) {
            asm volatile("s_waitcnt vmcnt(0)" ::: "memory");
            __builtin_amdgcn_s_barrier();
        }
    }
#undef STAGE_SK

    float bv[4];
#pragma unroll
    for (int nn = 0; nn < 4; ++nn)
        bv[nn] = (kz == 0) ? bias[n0 + wn + nn * 16 + fr] : 0.f;
#pragma unroll
    for (int mm = 0; mm < 4; ++mm) {
#pragma unroll
        for (int r = 0; r < 4; ++r) {
            const int m = wm + mm * 16 + (fq << 2) + r;
            if (m < valid) {
                int dst; float g;
                if constexpr (MOE) {
                    dst = tokmap[pass * 9984 + row0 + m];
                    g = rowgate[pass * 9984 + row0 + m];
                } else { dst = row0 + m; g = 1.f; }
                float* orow = out + (size_t)dst * N;
#pragma unroll
                for (int nn = 0; nn < 4; ++nn) {
                    const int n = n0 + wn + nn * 16 + fr;
                    atomicAdd(&orow[n], g * (acc[mm][nn][r] + bv[nn]));
                }
            }
        }
    }
}

// ---------------------------------------------------------------- GEMM (round-1 fallback)
template<int BLAYOUT, int EPI, bool MOE>
__global__ __launch_bounds__(256)
void gemm_k(const __bf16* __restrict__ A, const float* __restrict__ Bw,
            const float* __restrict__ bias, const float* __restrict__ resid,
            void* __restrict__ C, int N, int Kdim,
            const int* __restrict__ top_i, const float* __restrict__ gatesp,
            int pass, size_t bw_estride, int bias_estride)
{
    __shared__ __align__(16) __bf16 As[128][40];
    __shared__ __align__(16) __bf16 Bs[128][40];
    const int tid = threadIdx.x;
    int row0, valid;
    float gate = 1.0f;
    if constexpr (MOE) {
        const int b = blockIdx.y;
        row0 = b * SEQ; valid = SEQ;
        const int e = top_i[b * 2 + pass];
        Bw += (size_t)e * bw_estride;
        bias += (size_t)e * (size_t)bias_estride;
        gate = gatesp[b * 2 + pass];
    } else { row0 = blockIdx.y * 128; valid = 128; }
    const int n0 = blockIdx.x * 128;
    const int ar = tid >> 1, ac = (tid & 1) << 4;
    const int bk = tid & 31, bg = tid >> 5;
    const int wave = tid >> 6, lane = tid & 63;
    const int wm = (wave >> 1) << 6, wn = (wave & 1) << 6;
    const int fr = lane & 15, fq = lane >> 4;
    f32x4 acc[4][4];
#pragma unroll
    for (int i = 0; i < 4; ++i)
#pragma unroll
        for (int j = 0; j < 4; ++j) acc[i][j] = f32x4{0.f, 0.f, 0.f, 0.f};
    const bool a_ok = (!MOE) || (ar < valid);
    const __bf16* aptr = A + (size_t)(row0 + ar) * Kdim + ac;
    for (int k0 = 0; k0 < Kdim; k0 += 32) {
        uint4 a0 = {0, 0, 0, 0}, a1 = {0, 0, 0, 0};
        if (a_ok) {
            const uint4* ap = (const uint4*)(aptr + k0);
            a0 = ap[0]; a1 = ap[1];
        }
        float4 f0, f1, f2, f3;
        if constexpr (BLAYOUT == 0) {
            const float4* bp = (const float4*)(Bw + (size_t)(n0 + ar) * Kdim + k0 + ac);
            f0 = bp[0]; f1 = bp[1]; f2 = bp[2]; f3 = bp[3];
        } else {
            const float4* bp = (const float4*)(Bw + (size_t)(k0 + bk) * N + n0 + (bg << 4));
            f0 = bp[0]; f1 = bp[1]; f2 = bp[2]; f3 = bp[3];
        }
        __syncthreads();
        *(uint4*)&As[ar][ac] = a0;
        *(uint4*)&As[ar][ac + 8] = a1;
        if constexpr (BLAYOUT == 0) {
            bf16x8 h0, h1;
            h0[0]=(__bf16)f0.x; h0[1]=(__bf16)f0.y; h0[2]=(__bf16)f0.z; h0[3]=(__bf16)f0.w;
            h0[4]=(__bf16)f1.x; h0[5]=(__bf16)f1.y; h0[6]=(__bf16)f1.z; h0[7]=(__bf16)f1.w;
            h1[0]=(__bf16)f2.x; h1[1]=(__bf16)f2.y; h1[2]=(__bf16)f2.z; h1[3]=(__bf16)f2.w;
            h1[4]=(__bf16)f3.x; h1[5]=(__bf16)f3.y; h1[6]=(__bf16)f3.z; h1[7]=(__bf16)f3.w;
            *(bf16x8*)&Bs[ar][ac] = h0;
            *(bf16x8*)&Bs[ar][ac + 8] = h1;
        } else {
            const int nb = bg << 4;
            Bs[nb + 0][bk] = (__bf16)f0.x;  Bs[nb + 1][bk] = (__bf16)f0.y;
            Bs[nb + 2][bk] = (__bf16)f0.z;  Bs[nb + 3][bk] = (__bf16)f0.w;
            Bs[nb + 4][bk] = (__bf16)f1.x;  Bs[nb + 5][bk] = (__bf16)f1.y;
            Bs[nb + 6][bk] = (__bf16)f1.z;  Bs[nb + 7][bk] = (__bf16)f1.w;
            Bs[nb + 8][bk] = (__bf16)f2.x;  Bs[nb + 9][bk] = (__bf16)f2.y;
            Bs[nb + 10][bk] = (__bf16)f2.z; Bs[nb + 11][bk] = (__bf16)f2.w;
            Bs[nb + 12][bk] = (__bf16)f3.x; Bs[nb + 13][bk] = (__bf16)f3.y;
            Bs[nb + 14][bk] = (__bf16)f3.z; Bs[nb + 15][bk] = (__bf16)f3.w;
        }
        __syncthreads();
        bf16x8 af[4], bfr[4];
#pragma unroll
        for (int mm = 0; mm < 4; ++mm)
            af[mm] = *(const bf16x8*)&As[wm + mm * 16 + fr][fq << 3];
#pragma unroll
        for (int nn = 0; nn < 4; ++nn)
            bfr[nn] = *(const bf16x8*)&Bs[wn + nn * 16 + fr][fq << 3];
#pragma unroll
        for (int mm = 0; mm < 4; ++mm)
#pragma unroll
            for (int nn = 0; nn < 4; ++nn)
                acc[mm][nn] = __builtin_amdgcn_mfma_f32_16x16x32_bf16(
                    af[mm], bfr[nn], acc[mm][nn], 0, 0, 0);
    }
    float bv[4];
#pragma unroll
    for (int nn = 0; nn < 4; ++nn) bv[nn] = bias[n0 + wn + nn * 16 + fr];
#pragma unroll
    for (int mm = 0; mm < 4; ++mm) {
#pragma unroll
        for (int r = 0; r < 4; ++r) {
            const int m = wm + mm * 16 + (fq << 2) + r;
            if (!MOE || m < valid) {
                const size_t rowb = (size_t)(row0 + m) * N;
#pragma unroll
                for (int nn = 0; nn < 4; ++nn) {
                    const int n = n0 + wn + nn * 16 + fr;
                    float v = acc[mm][nn][r] + bv[nn];
                    if constexpr (EPI == 0) {
                        ((__bf16*)C)[rowb + n] = (__bf16)v;
                    } else if constexpr (EPI == 1) {
                        ((__bf16*)C)[rowb + n] = (__bf16)fmaxf(v, 0.f);
                    } else if constexpr (EPI == 2) {
                        ((float*)C)[rowb + n] = v + resid[rowb + n];
                    } else {
                        ((float*)C)[rowb + n] += gate * v;
                    }
                }
            }
        }
    }
}

// ---------------------------------------------------------------- launch
extern "C" void kernel_launch(void* const* d_in, const int* in_sizes, int n_in,
                              void* d_out, int out_size, void* d_ws, size_t ws_size,
                              hipStream_t stream)
{
    (void)in_sizes; (void)n_in; (void)out_size;
    const float* src      = (const float*)d_in[0];
    const float* packed_w = (const float*)d_in[1];
    const float* packed_b = (const float*)d_in[2];
    const float* out_w    = (const float*)d_in[3];
    const float* out_b    = (const float*)d_in[4];
    const float* ln1_w    = (const float*)d_in[5];
    const float* ln1_b    = (const float*)d_in[6];
    const float* ln2_w    = (const float*)d_in[7];
    const float* ln2_b    = (const float*)d_in[8];
    const float* router_w = (const float*)d_in[9];
    const float* ew1      = (const float*)d_in[10];
    const float* eb1      = (const float*)d_in[11];
    const float* ew2      = (const float*)d_in[12];
    const float* eb2      = (const float*)d_in[13];
    const float* sw1      = (const float*)d_in[14];
    const float* sb1      = (const float*)d_in[15];
    const float* sw2      = (const float*)d_in[16];
    const float* sb2      = (const float*)d_in[17];
    float* out = (float*)d_out;
    char* ws = (char*)d_ws;

    const size_t FULL_NEED = 261621760;
    if (ws_size >= FULL_NEED) {
        __bf16* w1T  = (__bf16*)(ws);                   // [9][4096][1024]
        __bf16* w2T  = (__bf16*)(ws + 75497472);        // [9][1024][4096]
        __bf16* pwB  = (__bf16*)(ws + 150994944);       // [3072][1024]
        __bf16* owB  = (__bf16*)(ws + 157286400);       // [1024][1024]
        __bf16* xn   = (__bf16*)(ws + 159383552);       // [9856][1024]
        int*    tokmap   = (int*)(ws + 179568640);      // [2][9984]
        float*  rowgate  = (float*)(ws + 179648512);    // [2][9984]
        int4*   tileinfo = (int4*)(ws + 179728384);     // [2][96]
        int*    ntiles   = (int*)(ws + 179731456);      // [2]
        char*   big  = ws + 179830784;
        __bf16* qkv  = (__bf16*)big;
        __bf16* ao   = (__bf16*)(big + 60555264);
        __bf16* hws  = (__bf16*)big;                    // 9984 x 4096
        int*    top_i = (int*)(ws + 261619712);
        float*  gates = (float*)(ws + 261619712 + 1024);

        // weight prep
        cvt_kernel<<<3072, 256, 0, stream>>>(packed_w, pwB, 786432);
        cvt_kernel<<<1024, 256, 0, stream>>>(out_w, owB, 262144);
        transpose_cvt<<<dim3(128, 32, 9), 256, 0, stream>>>(ew1, sw1, w1T, 1024, 4096);
        transpose_cvt<<<dim3(32, 128, 9), 256, 0, stream>>>(ew2, sw2, w2T, 4096, 1024);
        // attention block
        ln_kernel<<<NTOK, 256, 0, stream>>>(src, ln1_w, ln1_b, xn);
        gemm_bt<0, false><<<dim3(24, 77), 256, 0, stream>>>(
            xn, pwB, packed_b, nullptr, qkv, 3072, 1024, nullptr, nullptr, 0, 0, 0);
        attn_mfma<<<dim3(16, 128), 256, 0, stream>>>(qkv, ao);
        gemm_bt<2, false><<<dim3(8, 77), 256, 0, stream>>>(
            ao, owB, out_b, src, out, 1024, 1024, nullptr, nullptr, 0, 0, 0);
        // MoE block
        ln_kernel<<<NTOK, 256, 0, stream>>>(out, ln2_w, ln2_b, xn);
        router_kernel<<<128, 256, 0, stream>>>(out, ln2_w, ln2_b, router_w, top_i, gates);
        build_rowmap<<<1, 256, 0, stream>>>(top_i, gates, tokmap, rowgate,
                                            tileinfo, ntiles);
        for (int pass = 0; pass < 2; ++pass) {
            gemm_moe1<<<dim3(32, 84), 256, 0, stream>>>(
                xn, w1T, eb1, hws, tokmap, tileinfo, ntiles, pass);
            gemm_sk<true><<<dim3(8, 84, 4), 256, 0, stream>>>(
                hws, w2T, eb2, out, 1024, 4096,
                tokmap, rowgate, tileinfo, ntiles, pass);
        }
        gemm_bt<1, false><<<dim3(32, 77), 256, 0, stream>>>(
            xn, w1T + (size_t)8 * 4194304, sb1, nullptr, hws, 4096, 1024,
            nullptr, nullptr, 0, 0, 0);
        gemm_sk<false><<<dim3(8, 77, 4), 256, 0, stream>>>(
            hws, w2T + (size_t)8 * 4194304, sb2, out, 1024, 4096,
            nullptr, nullptr, nullptr, nullptr, 0);
    } else {
        // -------- round-1 fallback (fp32 weights) with MFMA attention --------
        __bf16* xn   = (__bf16*)(ws);
        __bf16* qkv  = (__bf16*)(ws + 20185088);
        __bf16* ao   = (__bf16*)(ws + 80740352);
        __bf16* hws  = (__bf16*)(ws + 20185088);
        __bf16* ffn  = xn;
        int*    top_i = (int*)(ws + 100925440);
        float*  gates = (float*)(ws + 100925440 + 1024);

        ln_kernel<<<NTOK, 256, 0, stream>>>(src, ln1_w, ln1_b, xn);
        gemm_k<0, 0, false><<<dim3(24, 77), 256, 0, stream>>>(
            xn, packed_w, packed_b, nullptr, qkv, 3072, 1024,
            nullptr, nullptr, 0, 0, 0);
        attn_mfma<<<dim3(16, 128), 256, 0, stream>>>(qkv, ao);
        gemm_k<0, 2, false><<<dim3(8, 77), 256, 0, stream>>>(
            ao, out_w, out_b, src, out, 1024, 1024,
            nullptr, nullptr, 0, 0, 0);
        ln_kernel<<<NTOK, 256, 0, stream>>>(out, ln2_w, ln2_b, ffn);
        router_kernel<<<128, 256, 0, stream>>>(out, ln2_w, ln2_b, router_w, top_i, gates);
        for (int pass = 0; pass < 2; ++pass) {
            gemm_k<1, 1, true><<<dim3(32, 128), 256, 0, stream>>>(
                ffn, ew1, eb1, nullptr, hws, 4096, 1024,
                top_i, gates, pass, (size_t)1024 * 4096, 4096);
            gemm_k<1, 3, true><<<dim3(8, 128), 256, 0, stream>>>(
                hws, ew2, eb2, nullptr, out, 1024, 4096,
                top_i, gates, pass, (size_t)4096 * 1024, 1024);
        }
        gemm_k<1, 1, false><<<dim3(32, 77), 256, 0, stream>>>(
            ffn, sw1, sb1, nullptr, hws, 4096, 1024,
            nullptr, nullptr, 0, 0, 0);
        gemm_k<1, 3, false><<<dim3(8, 77), 256, 0, stream>>>(
            hws, sw2, sb2, nullptr, out, 1024, 4096,
            nullptr, nullptr, 0, 0, 0);
    }
}

// Round 4
// 1660.730 us; speedup vs baseline: 1.0605x; 1.0124x over previous
//
#include <hip/hip_runtime.h>

// MyTransformerEncoderLayer: B=128,S=77,D=1024,H=16,DH=64,F=4096,E=8,topK=2
// Round 6: latency-bound diagnosis (all pipes <30% busy, occupancy 20% with
// 64KB dbuf). Fix: BK=32 double-buffer in 32KB LDS for all hot GEMMs ->
// 4-5 resident blocks/CU (2x latency coverage) while keeping the
// stage-before-compute pipeline. [128][32] LDS layout is conflict-free
// WITHOUT swizzle (row parity spreads banks; dword=16r+4fq uniform 8/bank).
// Expert-sorted MoE + split-K=4 down-proj + MFMA attention kept.
//
// ws layout unchanged, FULL_NEED = 261,621,760.

typedef float f32x4 __attribute__((ext_vector_type(4)));
typedef __bf16 bf16x8 __attribute__((ext_vector_type(8)));
typedef __bf16 bf16x4 __attribute__((ext_vector_type(4)));

#define NTOK 9856
#define DMODEL 1024
#define SEQ 77

__device__ __forceinline__ void gl16(const __bf16* g, __bf16* l) {
    __builtin_amdgcn_global_load_lds(
        (const __attribute__((address_space(1))) unsigned int*)g,
        (__attribute__((address_space(3))) unsigned int*)l, 16, 0, 0);
}

// ---------------------------------------------------------------- LayerNorm
__global__ __launch_bounds__(256)
void ln_kernel(const float* __restrict__ x, const float* __restrict__ w,
               const float* __restrict__ bb, __bf16* __restrict__ out)
{
    const int t = blockIdx.x, tid = threadIdx.x;
    const float4 v = ((const float4*)(x + (size_t)t * DMODEL))[tid];
    float s = v.x + v.y + v.z + v.w;
    float q = v.x*v.x + v.y*v.y + v.z*v.z + v.w*v.w;
#pragma unroll
    for (int off = 32; off; off >>= 1) {
        s += __shfl_xor(s, off, 64);
        q += __shfl_xor(q, off, 64);
    }
    __shared__ float rs[4], rq[4];
    const int wv = tid >> 6, lane = tid & 63;
    if (lane == 0) { rs[wv] = s; rq[wv] = q; }
    __syncthreads();
    s = rs[0] + rs[1] + rs[2] + rs[3];
    q = rq[0] + rq[1] + rq[2] + rq[3];
    const float mean = s * (1.f / 1024.f);
    const float rstd = rsqrtf(q * (1.f / 1024.f) - mean * mean + 1e-5f);
    const float4 wv4 = ((const float4*)w)[tid];
    const float4 bv4 = ((const float4*)bb)[tid];
    bf16x4 o;
    o[0] = (__bf16)((v.x - mean) * rstd * wv4.x + bv4.x);
    o[1] = (__bf16)((v.y - mean) * rstd * wv4.y + bv4.y);
    o[2] = (__bf16)((v.z - mean) * rstd * wv4.z + bv4.z);
    o[3] = (__bf16)((v.w - mean) * rstd * wv4.w + bv4.w);
    ((bf16x4*)out)[(size_t)t * 256 + tid] = o;
}

// ---------------------------------------------------------------- Router
__global__ __launch_bounds__(256)
void router_kernel(const float* __restrict__ x, const float* __restrict__ w,
                   const float* __restrict__ bb, const float* __restrict__ rw,
                   int* __restrict__ top_i, float* __restrict__ gates)
{
    const int b = blockIdx.x, tid = threadIdx.x;
    __shared__ float lnv[1024];
    __shared__ float red[8];
    __shared__ float pl[8][33];
    const float4 v = ((const float4*)(x + (size_t)b * SEQ * DMODEL))[tid];
    float s = v.x + v.y + v.z + v.w;
    float q = v.x*v.x + v.y*v.y + v.z*v.z + v.w*v.w;
#pragma unroll
    for (int off = 32; off; off >>= 1) {
        s += __shfl_xor(s, off, 64);
        q += __shfl_xor(q, off, 64);
    }
    const int wv = tid >> 6, lane = tid & 63;
    if (lane == 0) { red[wv] = s; red[4 + wv] = q; }
    __syncthreads();
    s = red[0] + red[1] + red[2] + red[3];
    q = red[4] + red[5] + red[6] + red[7];
    const float mean = s * (1.f / 1024.f);
    const float rstd = rsqrtf(q * (1.f / 1024.f) - mean * mean + 1e-5f);
    const float4 wv4 = ((const float4*)w)[tid];
    const float4 bv4 = ((const float4*)bb)[tid];
    lnv[4 * tid + 0] = (v.x - mean) * rstd * wv4.x + bv4.x;
    lnv[4 * tid + 1] = (v.y - mean) * rstd * wv4.y + bv4.y;
    lnv[4 * tid + 2] = (v.z - mean) * rstd * wv4.z + bv4.z;
    lnv[4 * tid + 3] = (v.w - mean) * rstd * wv4.w + bv4.w;
    __syncthreads();
    const int e = tid >> 5, g = tid & 31;
    float p = 0.f;
    for (int d = g; d < 1024; d += 32) p += lnv[d] * rw[(size_t)e * 1024 + d];
    pl[e][g] = p;
    __syncthreads();
    if (tid < 8) {
        float lg = 0.f;
        for (int i = 0; i < 32; ++i) lg += pl[tid][i];
        red[tid] = lg;
    }
    __syncthreads();
    if (tid == 0) {
        int i0 = 0; float v0 = red[0];
        for (int k = 1; k < 8; ++k) if (red[k] > v0) { v0 = red[k]; i0 = k; }
        int i1 = -1; float v1 = -3.4e38f;
        for (int k = 0; k < 8; ++k) if (k != i0 && red[k] > v1) { v1 = red[k]; i1 = k; }
        const float g1 = __expf(v1 - v0);
        const float invs = 1.f / (1.f + g1);
        top_i[b * 2] = i0; top_i[b * 2 + 1] = i1;
        gates[b * 2] = invs; gates[b * 2 + 1] = g1 * invs;
    }
}

// ---------------------------------------------------------------- MoE row map
__global__ __launch_bounds__(256)
void build_rowmap(const int* __restrict__ top_i, const float* __restrict__ gates,
                  int* __restrict__ tokmap, float* __restrict__ rowgate,
                  int4* __restrict__ tileinfo, int* __restrict__ ntiles)
{
    __shared__ int cnt[8];
    __shared__ int seqpos[128];
    const int tid = threadIdx.x;
    for (int pass = 0; pass < 2; ++pass) {
        if (tid < 8) cnt[tid] = 0;
        __syncthreads();
        if (tid < 128) atomicAdd(&cnt[top_i[tid * 2 + pass]], 1);
        __syncthreads();
        if (tid == 0) {
            int cur[8];
            int off = 0, nt = 0;
            for (int e = 0; e < 8; ++e) {
                cur[e] = off;
                const int len = 77 * cnt[e];
                for (int t = 0; t < len; t += 128) {
                    tileinfo[pass * 96 + nt] =
                        make_int4(off + t, (len - t) < 128 ? (len - t) : 128, e, 0);
                    ++nt;
                }
                off += len;
            }
            ntiles[pass] = nt;
            for (int b = 0; b < 128; ++b) {
                const int e = top_i[b * 2 + pass];
                seqpos[b] = cur[e];
                cur[e] += 77;
            }
        }
        __syncthreads();
        for (int c = tid; c < 9856; c += 256) {
            const int b = c / 77;
            const int dst = seqpos[b] + (c - b * 77);
            tokmap[pass * 9984 + dst] = c;
            rowgate[pass * 9984 + dst] = gates[b * 2 + pass];
        }
        for (int c = tid; c < 128; c += 256) {
            tokmap[pass * 9984 + 9856 + c] = 0;
            rowgate[pass * 9984 + 9856 + c] = 0.f;
        }
        __syncthreads();
    }
}

// ---------------------------------------------------------------- MFMA attention
__global__ __launch_bounds__(256)
void attn_mfma(const __bf16* __restrict__ qkv, __bf16* __restrict__ ao)
{
    const int h = blockIdx.x, b = blockIdx.y;
    const int tid = threadIdx.x;
    __shared__ __align__(16) char pool[64768];
    __bf16 (*Ks)[64] = (__bf16(*)[64])pool;
    __bf16 (*Vt)[96] = (__bf16(*)[96])(pool + 10240);
    float  (*Ss)[84] = (float (*)[84])(pool + 22528);
    __bf16 (*Qs)[64] = (__bf16(*)[64])(pool + 49408);
    __bf16 (*Ps)[96] = (__bf16(*)[96])(pool + 49408);

    const size_t base = (size_t)b * SEQ * 3072 + (size_t)h * 64;

    for (int c = tid; c < 77 * 8; c += 256) {
        const int s = c >> 3, d0 = (c & 7) << 3;
        *(bf16x8*)&Qs[s][d0] = *(const bf16x8*)&qkv[base + (size_t)s * 3072 + d0];
        *(bf16x8*)&Ks[s][d0] = *(const bf16x8*)&qkv[base + (size_t)s * 3072 + 1024 + d0];
    }
    for (int c = tid; c < 3 * 64; c += 256) {
        const int s = 77 + (c >> 6), d = c & 63;
        Qs[s][d] = (__bf16)0.f; Ks[s][d] = (__bf16)0.f;
    }
    for (int c = tid; c < 77 * 8; c += 256) {
        const int s = c >> 3, d0 = (c & 7) << 3;
        bf16x8 v = *(const bf16x8*)&qkv[base + (size_t)s * 3072 + 2048 + d0];
#pragma unroll
        for (int j = 0; j < 8; ++j) Vt[d0 + j][s] = v[j];
    }
    for (int c = tid; c < 64 * 19; c += 256) {
        const int d = c / 19, s = 77 + c % 19;
        Vt[d][s] = (__bf16)0.f;
    }
    __syncthreads();

    const int wv = tid >> 6, ln = tid & 63;
    const int fr = ln & 15, fq = ln >> 4;

    for (int f = wv; f < 25; f += 4) {
        const int mt = f / 5, nt = f - mt * 5;
        bf16x8 a0 = *(const bf16x8*)&Qs[mt * 16 + fr][fq * 8];
        bf16x8 a1 = *(const bf16x8*)&Qs[mt * 16 + fr][32 + fq * 8];
        bf16x8 b0 = *(const bf16x8*)&Ks[nt * 16 + fr][fq * 8];
        bf16x8 b1 = *(const bf16x8*)&Ks[nt * 16 + fr][32 + fq * 8];
        f32x4 acc = {0.f, 0.f, 0.f, 0.f};
        acc = __builtin_amdgcn_mfma_f32_16x16x32_bf16(a0, b0, acc, 0, 0, 0);
        acc = __builtin_amdgcn_mfma_f32_16x16x32_bf16(a1, b1, acc, 0, 0, 0);
#pragma unroll
        for (int r = 0; r < 4; ++r)
            Ss[mt * 16 + fq * 4 + r][nt * 16 + fr] = acc[r] * 0.125f;
    }
    __syncthreads();

    if (tid < 80) {
        float mx = -1e30f;
        for (int c = 0; c < 77; ++c) mx = fmaxf(mx, Ss[tid][c]);
        float sum = 0.f;
        for (int c = 0; c < 77; ++c) {
            const float e2 = __expf(Ss[tid][c] - mx);
            Ss[tid][c] = e2; sum += e2;
        }
        const float inv = 1.f / sum;
        for (int c = 0; c < 77; ++c) Ps[tid][c] = (__bf16)(Ss[tid][c] * inv);
        for (int c = 77; c < 96; ++c) Ps[tid][c] = (__bf16)0.f;
    }
    __syncthreads();

    for (int f = wv; f < 20; f += 4) {
        const int mt = f >> 2, nt = f & 3;
        f32x4 acc = {0.f, 0.f, 0.f, 0.f};
#pragma unroll
        for (int kk = 0; kk < 3; ++kk) {
            bf16x8 a = *(const bf16x8*)&Ps[mt * 16 + fr][kk * 32 + fq * 8];
            bf16x8 bb = *(const bf16x8*)&Vt[nt * 16 + fr][kk * 32 + fq * 8];
            acc = __builtin_amdgcn_mfma_f32_16x16x32_bf16(a, bb, acc, 0, 0, 0);
        }
#pragma unroll
        for (int r = 0; r < 4; ++r) {
            const int m = mt * 16 + fq * 4 + r;
            if (m < 77)
                ao[((size_t)b * SEQ + m) * DMODEL + (size_t)h * 64 + nt * 16 + fr]
                    = (__bf16)acc[r];
        }
    }
}

// ---------------------------------------------------------------- weight prep
__global__ __launch_bounds__(256)
void cvt_kernel(const float* __restrict__ in, __bf16* __restrict__ out, int n4)
{
    const int i = blockIdx.x * 256 + threadIdx.x;
    if (i < n4) {
        const float4 v = ((const float4*)in)[i];
        bf16x4 o;
        o[0] = (__bf16)v.x; o[1] = (__bf16)v.y; o[2] = (__bf16)v.z; o[3] = (__bf16)v.w;
        ((bf16x4*)out)[i] = o;
    }
}

__global__ __launch_bounds__(256)
void transpose_cvt(const float* __restrict__ e_in, const float* __restrict__ s_in,
                   __bf16* __restrict__ outw, int R, int C)
{
    const int z = blockIdx.z;
    const float* in = (z == 8) ? s_in : e_in + (size_t)z * R * C;
    __bf16* out = outw + (size_t)z * R * C;
    __shared__ float t[32][33];
    const int tr = threadIdx.x >> 3, tc4 = (threadIdx.x & 7) << 2;
    const int r0 = blockIdx.y << 5, c0 = blockIdx.x << 5;
    const float4 v = *(const float4*)&in[(size_t)(r0 + tr) * C + c0 + tc4];
    t[tr][tc4 + 0] = v.x; t[tr][tc4 + 1] = v.y;
    t[tr][tc4 + 2] = v.z; t[tr][tc4 + 3] = v.w;
    __syncthreads();
    bf16x4 o;
    o[0] = (__bf16)t[tc4 + 0][tr]; o[1] = (__bf16)t[tc4 + 1][tr];
    o[2] = (__bf16)t[tc4 + 2][tr]; o[3] = (__bf16)t[tc4 + 3][tr];
    *(bf16x4*)&out[(size_t)(c0 + tr) * R + r0 + tc4] = o;
}

// ============================================================================
// BK=32 double-buffered GEMM core, 32KB LDS total (4-5 blocks/CU).
// LDS [2][128][32] per operand: staging dest linear (gl16: 1KB = 16 rows x
// 64B; lane ln -> row ln>>2, 16B slot ln&3). Reads As[r][fq*8] are
// conflict-free: dword = 16r + 4fq -> row parity + fq give uniform 8/bank.
// Per K-step: stage next tile (4 gl16/wave), 16 MFMA, vmcnt(0)+barrier.
// ============================================================================

#define GEMM_STEP(CUR)                                                         \
    {                                                                          \
        bf16x8 af[4], bf[4];                                                   \
        _Pragma("unroll")                                                      \
        for (int mm = 0; mm < 4; ++mm)                                         \
            af[mm] = *(const bf16x8*)&As[CUR][wm + mm * 16 + fr][fq * 8];      \
        _Pragma("unroll")                                                      \
        for (int nn = 0; nn < 4; ++nn)                                         \
            bf[nn] = *(const bf16x8*)&Bs[CUR][wn + nn * 16 + fr][fq * 8];      \
        _Pragma("unroll")                                                      \
        for (int mm = 0; mm < 4; ++mm)                                         \
            _Pragma("unroll")                                                  \
            for (int nn = 0; nn < 4; ++nn)                                     \
                acc[mm][nn] = __builtin_amdgcn_mfma_f32_16x16x32_bf16(         \
                    af[mm], bf[nn], acc[mm][nn], 0, 0, 0);                     \
    }

#define GEMM_SYNC()                                                            \
    asm volatile("s_waitcnt vmcnt(0)" ::: "memory");                           \
    __builtin_amdgcn_s_barrier();

// ---------------------------------------------------------------- GEMM (bf16 BT)
// EPI 0: bias->bf16  1: bias+relu->bf16  2: bias+resid->fp32  3: fp32 += bias+v
template<int EPI, bool MOE>
__global__ __launch_bounds__(256)
void gemm_bt(const __bf16* __restrict__ A, const __bf16* __restrict__ Bw,
             const float* __restrict__ bias, const float* __restrict__ resid,
             void* __restrict__ C, int N, int Kdim,
             const int* __restrict__ top_i, const float* __restrict__ gatesp,
             int pass, size_t bw_estride, int bias_estride)
{
    __shared__ __align__(16) __bf16 As[2][128][32];
    __shared__ __align__(16) __bf16 Bs[2][128][32];
    const int tid = threadIdx.x;
    int row0, valid;
    float gate = 1.f;
    if constexpr (MOE) {
        const int b = blockIdx.y;
        row0 = b * SEQ; valid = SEQ;
        const int e = top_i[b * 2 + pass];
        Bw += (size_t)e * bw_estride;
        bias += (size_t)e * (size_t)bias_estride;
        gate = gatesp[b * 2 + pass];
    } else { row0 = blockIdx.y * 128; valid = 128; }
    const int n0 = blockIdx.x * 128;

    const int wv = tid >> 6, ln = tid & 63;
    const int sr = wv * 32 + (ln >> 2), sc = (ln & 3) << 3;
    const __bf16* ag0 = A + (size_t)(row0 + sr) * Kdim + sc;
    const __bf16* ag1 = ag0 + (size_t)16 * Kdim;
    const __bf16* bg0 = Bw + (size_t)(n0 + sr) * Kdim + sc;
    const __bf16* bg1 = bg0 + (size_t)16 * Kdim;

    const int fr = ln & 15, fq = ln >> 4;
    const int wm = (wv >> 1) << 6, wn = (wv & 1) << 6;

    f32x4 acc[4][4];
#pragma unroll
    for (int i = 0; i < 4; ++i)
#pragma unroll
        for (int j = 0; j < 4; ++j) acc[i][j] = f32x4{0.f, 0.f, 0.f, 0.f};

    int sbuf = 0;
#define STAGE_BT()                                                             \
    {                                                                          \
        __bf16* asl = &As[sbuf][wv * 32][0];                                   \
        __bf16* bsl = &Bs[sbuf][wv * 32][0];                                   \
        gl16(ag0, asl); gl16(ag1, asl + 512);                                  \
        gl16(bg0, bsl); gl16(bg1, bsl + 512);                                  \
        ag0 += 32; ag1 += 32; bg0 += 32; bg1 += 32; sbuf ^= 1;                 \
    }

    const int nk = Kdim >> 5;
    STAGE_BT();
    GEMM_SYNC();
    for (int kt = 0; kt < nk; ++kt) {
        const int cur = kt & 1;
        if (kt + 1 < nk) STAGE_BT();
        GEMM_STEP(cur);
        if (kt + 1 < nk) { GEMM_SYNC(); }
    }
#undef STAGE_BT

    float bv[4];
#pragma unroll
    for (int nn = 0; nn < 4; ++nn) bv[nn] = bias[n0 + wn + nn * 16 + fr];
#pragma unroll
    for (int mm = 0; mm < 4; ++mm) {
#pragma unroll
        for (int r = 0; r < 4; ++r) {
            const int m = wm + mm * 16 + (fq << 2) + r;
            if (!MOE || m < valid) {
                const size_t rowb = (size_t)(row0 + m) * N;
#pragma unroll
                for (int nn = 0; nn < 4; ++nn) {
                    const int n = n0 + wn + nn * 16 + fr;
                    float v = acc[mm][nn][r] + bv[nn];
                    if constexpr (EPI == 0) {
                        ((__bf16*)C)[rowb + n] = (__bf16)v;
                    } else if constexpr (EPI == 1) {
                        ((__bf16*)C)[rowb + n] = (__bf16)fmaxf(v, 0.f);
                    } else if constexpr (EPI == 2) {
                        ((float*)C)[rowb + n] = v + resid[rowb + n];
                    } else {
                        ((float*)C)[rowb + n] += gate * v;
                    }
                }
            }
        }
    }
}

// ---------------------------------------------------------------- MoE GEMM 1
// xn gathered via tokmap -> h (sorted rows). K=1024, N=4096. bias+relu.
__global__ __launch_bounds__(256)
void gemm_moe1(const __bf16* __restrict__ A, const __bf16* __restrict__ w1T,
               const float* __restrict__ eb1, __bf16* __restrict__ h,
               const int* __restrict__ tokmap, const int4* __restrict__ tileinfo,
               const int* __restrict__ ntiles, int pass)
{
    const int tile = blockIdx.y;
    if (tile >= ntiles[pass]) return;
    __shared__ __align__(16) __bf16 As[2][128][32];
    __shared__ __align__(16) __bf16 Bs[2][128][32];
    const int4 ti = tileinfo[pass * 96 + tile];
    const int row0 = ti.x, valid = ti.y;
    const __bf16* Bw = w1T + (size_t)ti.z * 4194304;
    const float* bias = eb1 + (size_t)ti.z * 4096;
    const int n0 = blockIdx.x * 128;
    const int tid = threadIdx.x;
    const int wv = tid >> 6, ln = tid & 63;
    const int sr = wv * 32 + (ln >> 2), sc = (ln & 3) << 3;
    const int* tm = tokmap + pass * 9984 + row0;
    const __bf16* ag0 = A + (size_t)tm[sr] * 1024 + sc;
    const __bf16* ag1 = A + (size_t)tm[sr + 16] * 1024 + sc;
    const __bf16* bg0 = Bw + (size_t)(n0 + sr) * 1024 + sc;
    const __bf16* bg1 = bg0 + (size_t)16 * 1024;
    const int fr = ln & 15, fq = ln >> 4;
    const int wm = (wv >> 1) << 6, wn = (wv & 1) << 6;

    f32x4 acc[4][4];
#pragma unroll
    for (int i = 0; i < 4; ++i)
#pragma unroll
        for (int j = 0; j < 4; ++j) acc[i][j] = f32x4{0.f, 0.f, 0.f, 0.f};

    int sbuf = 0;
#define STAGE_M1()                                                             \
    {                                                                          \
        __bf16* asl = &As[sbuf][wv * 32][0];                                   \
        __bf16* bsl = &Bs[sbuf][wv * 32][0];                                   \
        gl16(ag0, asl); gl16(ag1, asl + 512);                                  \
        gl16(bg0, bsl); gl16(bg1, bsl + 512);                                  \
        ag0 += 32; ag1 += 32; bg0 += 32; bg1 += 32; sbuf ^= 1;                 \
    }

    STAGE_M1();
    GEMM_SYNC();
    for (int kt = 0; kt < 32; ++kt) {
        const int cur = kt & 1;
        if (kt + 1 < 32) STAGE_M1();
        GEMM_STEP(cur);
        if (kt + 1 < 32) { GEMM_SYNC(); }
    }
#undef STAGE_M1

    float bv[4];
#pragma unroll
    for (int nn = 0; nn < 4; ++nn) bv[nn] = bias[n0 + wn + nn * 16 + fr];
#pragma unroll
    for (int mm = 0; mm < 4; ++mm) {
#pragma unroll
        for (int r = 0; r < 4; ++r) {
            const int m = wm + mm * 16 + (fq << 2) + r;
            if (m < valid) {
                __bf16* hr = h + (size_t)(row0 + m) * 4096;
#pragma unroll
                for (int nn = 0; nn < 4; ++nn) {
                    const int n = n0 + wn + nn * 16 + fr;
                    hr[n] = (__bf16)fmaxf(acc[mm][nn][r] + bv[nn], 0.f);
                }
            }
        }
    }
}

// ---------------------------------------------------------------- split-K GEMM
// K=4096 -> N=1024 down-projections. grid (8, Mtiles, 4). fp32 atomicAdd,
// bias added by kz==0 only.
template<bool MOE>
__global__ __launch_bounds__(256)
void gemm_sk(const __bf16* __restrict__ A, const __bf16* __restrict__ Bw,
             const float* __restrict__ bias, float* __restrict__ out,
             int N, int Kdim,
             const int* __restrict__ tokmap, const float* __restrict__ rowgate,
             const int4* __restrict__ tileinfo, const int* __restrict__ ntiles,
             int pass)
{
    int row0, valid;
    if constexpr (MOE) {
        const int tile = blockIdx.y;
        if (tile >= ntiles[pass]) return;
        const int4 ti = tileinfo[pass * 96 + tile];
        row0 = ti.x; valid = ti.y;
        Bw += (size_t)ti.z * ((size_t)N * Kdim);
        bias += (size_t)ti.z * N;
    } else { row0 = blockIdx.y * 128; valid = 128; }
    __shared__ __align__(16) __bf16 As[2][128][32];
    __shared__ __align__(16) __bf16 Bs[2][128][32];
    const int n0 = blockIdx.x * 128;
    const int kz = blockIdx.z;
    const int kchunk = Kdim >> 2;              // SPLITK = 4
    const int koff = kz * kchunk;
    const int tid = threadIdx.x;
    const int wv = tid >> 6, ln = tid & 63;
    const int sr = wv * 32 + (ln >> 2), sc = (ln & 3) << 3;
    const __bf16* ag0 = A + (size_t)(row0 + sr) * Kdim + koff + sc;
    const __bf16* ag1 = ag0 + (size_t)16 * Kdim;
    const __bf16* bg0 = Bw + (size_t)(n0 + sr) * Kdim + koff + sc;
    const __bf16* bg1 = bg0 + (size_t)16 * Kdim;
    const int fr = ln & 15, fq = ln >> 4;
    const int wm = (wv >> 1) << 6, wn = (wv & 1) << 6;

    f32x4 acc[4][4];
#pragma unroll
    for (int i = 0; i < 4; ++i)
#pragma unroll
        for (int j = 0; j < 4; ++j) acc[i][j] = f32x4{0.f, 0.f, 0.f, 0.f};

    int sbuf = 0;
#define STAGE_SK()                                                             \
    {                                                                          \
        __bf16* asl = &As[sbuf][wv * 32][0];                                   \
        __bf16* bsl = &Bs[sbuf][wv * 32][0];                                   \
        gl16(ag0, asl); gl16(ag1, asl + 512);                                  \
        gl16(bg0, bsl); gl16(bg1, bsl + 512);                                  \
        ag0 += 32; ag1 += 32; bg0 += 32; bg1 += 32; sbuf ^= 1;                 \
    }

    const int nk = kchunk >> 5;
    STAGE_SK();
    GEMM_SYNC();
    for (int kt = 0; kt < nk; ++kt) {
        const int cur = kt & 1;
        if (kt + 1 < nk) STAGE_SK();
        GEMM_STEP(cur);
        if (kt + 1 < nk) { GEMM_SYNC(); }
    }
#undef STAGE_SK

    float bv[4];
#pragma unroll
    for (int nn = 0; nn < 4; ++nn)
        bv[nn] = (kz == 0) ? bias[n0 + wn + nn * 16 + fr] : 0.f;
#pragma unroll
    for (int mm = 0; mm < 4; ++mm) {
#pragma unroll
        for (int r = 0; r < 4; ++r) {
            const int m = wm + mm * 16 + (fq << 2) + r;
            if (m < valid) {
                int dst; float g;
                if constexpr (MOE) {
                    dst = tokmap[pass * 9984 + row0 + m];
                    g = rowgate[pass * 9984 + row0 + m];
                } else { dst = row0 + m; g = 1.f; }
                float* orow = out + (size_t)dst * N;
#pragma unroll
                for (int nn = 0; nn < 4; ++nn) {
                    const int n = n0 + wn + nn * 16 + fr;
                    atomicAdd(&orow[n], g * (acc[mm][nn][r] + bv[nn]));
                }
            }
        }
    }
}

// ---------------------------------------------------------------- GEMM (round-1 fallback)
template<int BLAYOUT, int EPI, bool MOE>
__global__ __launch_bounds__(256)
void gemm_k(const __bf16* __restrict__ A, const float* __restrict__ Bw,
            const float* __restrict__ bias, const float* __restrict__ resid,
            void* __restrict__ C, int N, int Kdim,
            const int* __restrict__ top_i, const float* __restrict__ gatesp,
            int pass, size_t bw_estride, int bias_estride)
{
    __shared__ __align__(16) __bf16 As[128][40];
    __shared__ __align__(16) __bf16 Bs[128][40];
    const int tid = threadIdx.x;
    int row0, valid;
    float gate = 1.0f;
    if constexpr (MOE) {
        const int b = blockIdx.y;
        row0 = b * SEQ; valid = SEQ;
        const int e = top_i[b * 2 + pass];
        Bw += (size_t)e * bw_estride;
        bias += (size_t)e * (size_t)bias_estride;
        gate = gatesp[b * 2 + pass];
    } else { row0 = blockIdx.y * 128; valid = 128; }
    const int n0 = blockIdx.x * 128;
    const int ar = tid >> 1, ac = (tid & 1) << 4;
    const int bk = tid & 31, bg = tid >> 5;
    const int wave = tid >> 6, lane = tid & 63;
    const int wm = (wave >> 1) << 6, wn = (wave & 1) << 6;
    const int fr = lane & 15, fq = lane >> 4;
    f32x4 acc[4][4];
#pragma unroll
    for (int i = 0; i < 4; ++i)
#pragma unroll
        for (int j = 0; j < 4; ++j) acc[i][j] = f32x4{0.f, 0.f, 0.f, 0.f};
    const bool a_ok = (!MOE) || (ar < valid);
    const __bf16* aptr = A + (size_t)(row0 + ar) * Kdim + ac;
    for (int k0 = 0; k0 < Kdim; k0 += 32) {
        uint4 a0 = {0, 0, 0, 0}, a1 = {0, 0, 0, 0};
        if (a_ok) {
            const uint4* ap = (const uint4*)(aptr + k0);
            a0 = ap[0]; a1 = ap[1];
        }
        float4 f0, f1, f2, f3;
        if constexpr (BLAYOUT == 0) {
            const float4* bp = (const float4*)(Bw + (size_t)(n0 + ar) * Kdim + k0 + ac);
            f0 = bp[0]; f1 = bp[1]; f2 = bp[2]; f3 = bp[3];
        } else {
            const float4* bp = (const float4*)(Bw + (size_t)(k0 + bk) * N + n0 + (bg << 4));
            f0 = bp[0]; f1 = bp[1]; f2 = bp[2]; f3 = bp[3];
        }
        __syncthreads();
        *(uint4*)&As[ar][ac] = a0;
        *(uint4*)&As[ar][ac + 8] = a1;
        if constexpr (BLAYOUT == 0) {
            bf16x8 h0, h1;
            h0[0]=(__bf16)f0.x; h0[1]=(__bf16)f0.y; h0[2]=(__bf16)f0.z; h0[3]=(__bf16)f0.w;
            h0[4]=(__bf16)f1.x; h0[5]=(__bf16)f1.y; h0[6]=(__bf16)f1.z; h0[7]=(__bf16)f1.w;
            h1[0]=(__bf16)f2.x; h1[1]=(__bf16)f2.y; h1[2]=(__bf16)f2.z; h1[3]=(__bf16)f2.w;
            h1[4]=(__bf16)f3.x; h1[5]=(__bf16)f3.y; h1[6]=(__bf16)f3.z; h1[7]=(__bf16)f3.w;
            *(bf16x8*)&Bs[ar][ac] = h0;
            *(bf16x8*)&Bs[ar][ac + 8] = h1;
        } else {
            const int nb = bg << 4;
            Bs[nb + 0][bk] = (__bf16)f0.x;  Bs[nb + 1][bk] = (__bf16)f0.y;
            Bs[nb + 2][bk] = (__bf16)f0.z;  Bs[nb + 3][bk] = (__bf16)f0.w;
            Bs[nb + 4][bk] = (__bf16)f1.x;  Bs[nb + 5][bk] = (__bf16)f1.y;
            Bs[nb + 6][bk] = (__bf16)f1.z;  Bs[nb + 7][bk] = (__bf16)f1.w;
            Bs[nb + 8][bk] = (__bf16)f2.x;  Bs[nb + 9][bk] = (__bf16)f2.y;
            Bs[nb + 10][bk] = (__bf16)f2.z; Bs[nb + 11][bk] = (__bf16)f2.w;
            Bs[nb + 12][bk] = (__bf16)f3.x; Bs[nb + 13][bk] = (__bf16)f3.y;
            Bs[nb + 14][bk] = (__bf16)f3.z; Bs[nb + 15][bk] = (__bf16)f3.w;
        }
        __syncthreads();
        bf16x8 af[4], bfr[4];
#pragma unroll
        for (int mm = 0; mm < 4; ++mm)
            af[mm] = *(const bf16x8*)&As[wm + mm * 16 + fr][fq << 3];
#pragma unroll
        for (int nn = 0; nn < 4; ++nn)
            bfr[nn] = *(const bf16x8*)&Bs[wn + nn * 16 + fr][fq << 3];
#pragma unroll
        for (int mm = 0; mm < 4; ++mm)
#pragma unroll
            for (int nn = 0; nn < 4; ++nn)
                acc[mm][nn] = __builtin_amdgcn_mfma_f32_16x16x32_bf16(
                    af[mm], bfr[nn], acc[mm][nn], 0, 0, 0);
    }
    float bv[4];
#pragma unroll
    for (int nn = 0; nn < 4; ++nn) bv[nn] = bias[n0 + wn + nn * 16 + fr];
#pragma unroll
    for (int mm = 0; mm < 4; ++mm) {
#pragma unroll
        for (int r = 0; r < 4; ++r) {
            const int m = wm + mm * 16 + (fq << 2) + r;
            if (!MOE || m < valid) {
                const size_t rowb = (size_t)(row0 + m) * N;
#pragma unroll
                for (int nn = 0; nn < 4; ++nn) {
                    const int n = n0 + wn + nn * 16 + fr;
                    float v = acc[mm][nn][r] + bv[nn];
                    if constexpr (EPI == 0) {
                        ((__bf16*)C)[rowb + n] = (__bf16)v;
                    } else if constexpr (EPI == 1) {
                        ((__bf16*)C)[rowb + n] = (__bf16)fmaxf(v, 0.f);
                    } else if constexpr (EPI == 2) {
                        ((float*)C)[rowb + n] = v + resid[rowb + n];
                    } else {
                        ((float*)C)[rowb + n] += gate * v;
                    }
                }
            }
        }
    }
}

// ---------------------------------------------------------------- launch
extern "C" void kernel_launch(void* const* d_in, const int* in_sizes, int n_in,
                              void* d_out, int out_size, void* d_ws, size_t ws_size,
                              hipStream_t stream)
{
    (void)in_sizes; (void)n_in; (void)out_size;
    const float* src      = (const float*)d_in[0];
    const float* packed_w = (const float*)d_in[1];
    const float* packed_b = (const float*)d_in[2];
    const float* out_w    = (const float*)d_in[3];
    const float* out_b    = (const float*)d_in[4];
    const float* ln1_w    = (const float*)d_in[5];
    const float* ln1_b    = (const float*)d_in[6];
    const float* ln2_w    = (const float*)d_in[7];
    const float* ln2_b    = (const float*)d_in[8];
    const float* router_w = (const float*)d_in[9];
    const float* ew1      = (const float*)d_in[10];
    const float* eb1      = (const float*)d_in[11];
    const float* ew2      = (const float*)d_in[12];
    const float* eb2      = (const float*)d_in[13];
    const float* sw1      = (const float*)d_in[14];
    const float* sb1      = (const float*)d_in[15];
    const float* sw2      = (const float*)d_in[16];
    const float* sb2      = (const float*)d_in[17];
    float* out = (float*)d_out;
    char* ws = (char*)d_ws;

    const size_t FULL_NEED = 261621760;
    if (ws_size >= FULL_NEED) {
        __bf16* w1T  = (__bf16*)(ws);                   // [9][4096][1024]
        __bf16* w2T  = (__bf16*)(ws + 75497472);        // [9][1024][4096]
        __bf16* pwB  = (__bf16*)(ws + 150994944);       // [3072][1024]
        __bf16* owB  = (__bf16*)(ws + 157286400);       // [1024][1024]
        __bf16* xn   = (__bf16*)(ws + 159383552);       // [9856][1024]
        int*    tokmap   = (int*)(ws + 179568640);      // [2][9984]
        float*  rowgate  = (float*)(ws + 179648512);    // [2][9984]
        int4*   tileinfo = (int4*)(ws + 179728384);     // [2][96]
        int*    ntiles   = (int*)(ws + 179731456);      // [2]
        char*   big  = ws + 179830784;
        __bf16* qkv  = (__bf16*)big;
        __bf16* ao   = (__bf16*)(big + 60555264);
        __bf16* hws  = (__bf16*)big;                    // 9984 x 4096
        int*    top_i = (int*)(ws + 261619712);
        float*  gates = (float*)(ws + 261619712 + 1024);

        // weight prep
        cvt_kernel<<<3072, 256, 0, stream>>>(packed_w, pwB, 786432);
        cvt_kernel<<<1024, 256, 0, stream>>>(out_w, owB, 262144);
        transpose_cvt<<<dim3(128, 32, 9), 256, 0, stream>>>(ew1, sw1, w1T, 1024, 4096);
        transpose_cvt<<<dim3(32, 128, 9), 256, 0, stream>>>(ew2, sw2, w2T, 4096, 1024);
        // attention block
        ln_kernel<<<NTOK, 256, 0, stream>>>(src, ln1_w, ln1_b, xn);
        gemm_bt<0, false><<<dim3(24, 77), 256, 0, stream>>>(
            xn, pwB, packed_b, nullptr, qkv, 3072, 1024, nullptr, nullptr, 0, 0, 0);
        attn_mfma<<<dim3(16, 128), 256, 0, stream>>>(qkv, ao);
        gemm_bt<2, false><<<dim3(8, 77), 256, 0, stream>>>(
            ao, owB, out_b, src, out, 1024, 1024, nullptr, nullptr, 0, 0, 0);
        // MoE block
        ln_kernel<<<NTOK, 256, 0, stream>>>(out, ln2_w, ln2_b, xn);
        router_kernel<<<128, 256, 0, stream>>>(out, ln2_w, ln2_b, router_w, top_i, gates);
        build_rowmap<<<1, 256, 0, stream>>>(top_i, gates, tokmap, rowgate,
                                            tileinfo, ntiles);
        for (int pass = 0; pass < 2; ++pass) {
            gemm_moe1<<<dim3(32, 84), 256, 0, stream>>>(
                xn, w1T, eb1, hws, tokmap, tileinfo, ntiles, pass);
            gemm_sk<true><<<dim3(8, 84, 4), 256, 0, stream>>>(
                hws, w2T, eb2, out, 1024, 4096,
                tokmap, rowgate, tileinfo, ntiles, pass);
        }
        gemm_bt<1, false><<<dim3(32, 77), 256, 0, stream>>>(
            xn, w1T + (size_t)8 * 4194304, sb1, nullptr, hws, 4096, 1024,
            nullptr, nullptr, 0, 0, 0);
        gemm_sk<false><<<dim3(8, 77, 4), 256, 0, stream>>>(
            hws, w2T + (size_t)8 * 4194304, sb2, out, 1024, 4096,
            nullptr, nullptr, nullptr, nullptr, 0);
    } else {
        // -------- round-1 fallback (fp32 weights) with MFMA attention --------
        __bf16* xn   = (__bf16*)(ws);
        __bf16* qkv  = (__bf16*)(ws + 20185088);
        __bf16* ao   = (__bf16*)(ws + 80740352);
        __bf16* hws  = (__bf16*)(ws + 20185088);
        __bf16* ffn  = xn;
        int*    top_i = (int*)(ws + 100925440);
        float*  gates = (float*)(ws + 100925440 + 1024);

        ln_kernel<<<NTOK, 256, 0, stream>>>(src, ln1_w, ln1_b, xn);
        gemm_k<0, 0, false><<<dim3(24, 77), 256, 0, stream>>>(
            xn, packed_w, packed_b, nullptr, qkv, 3072, 1024,
            nullptr, nullptr, 0, 0, 0);
        attn_mfma<<<dim3(16, 128), 256, 0, stream>>>(qkv, ao);
        gemm_k<0, 2, false><<<dim3(8, 77), 256, 0, stream>>>(
            ao, out_w, out_b, src, out, 1024, 1024,
            nullptr, nullptr, 0, 0, 0);
        ln_kernel<<<NTOK, 256, 0, stream>>>(out, ln2_w, ln2_b, ffn);
        router_kernel<<<128, 256, 0, stream>>>(out, ln2_w, ln2_b, router_w, top_i, gates);
        for (int pass = 0; pass < 2; ++pass) {
            gemm_k<1, 1, true><<<dim3(32, 128), 256, 0, stream>>>(
                ffn, ew1, eb1, nullptr, hws, 4096, 1024,
                top_i, gates, pass, (size_t)1024 * 4096, 4096);
            gemm_k<1, 3, true><<<dim3(8, 128), 256, 0, stream>>>(
                hws, ew2, eb2, nullptr, out, 1024, 4096,
                top_i, gates, pass, (size_t)4096 * 1024, 1024);
        }
        gemm_k<1, 1, false><<<dim3(32, 77), 256, 0, stream>>>(
            ffn, sw1, sb1, nullptr, hws, 4096, 1024,
            nullptr, nullptr, 0, 0, 0);
        gemm_k<1, 3, false><<<dim3(8, 77), 256, 0, stream>>>(
            hws, sw2, sb2, nullptr, out, 1024, 4096,
            nullptr, nullptr, 0, 0, 0);
    }
}